// Round 1
// baseline (779.654 us; speedup 1.0000x reference)
//
#include <hip/hip_runtime.h>
#include <math.h>

#define D     512
#define KCB   1024
#define TB    16
#define NT    256
#define ALPHA 10.0f

__device__ __forceinline__ float wave_reduce_sum(float v) {
    #pragma unroll
    for (int off = 32; off >= 1; off >>= 1) v += __shfl_xor(v, off, 64);
    return v;
}

// ---------------- K0: zero the ws accumulators (ws is poisoned 0xAA each call)
__global__ void k_init(float* __restrict__ avg, float* __restrict__ sse, float* __restrict__ clu) {
    int t = threadIdx.x + blockIdx.x * blockDim.x;
    if (t < KCB) avg[t] = 0.0f;
    if (t == 0) { *sse = 0.0f; *clu = 0.0f; }
}

// ---------------- K1: cbT[d][k] = normalize(emb[k])[d]  (transposed for coalesced attention reads)
__global__ __launch_bounds__(NT) void k_cbt(const float* __restrict__ emb, float* __restrict__ cbT) {
    const int k = blockIdx.x;
    const int t = threadIdx.x;
    const int wv = t >> 6, lane = t & 63;
    const float2* e2 = (const float2*)(emb + (size_t)k * D);
    float2 v = e2[t];                      // d = 2t, 2t+1
    float ss = v.x * v.x + v.y * v.y;
    ss = wave_reduce_sum(ss);
    __shared__ float part[4];
    __shared__ float s_inv;
    if (lane == 0) part[wv] = ss;
    __syncthreads();
    if (t == 0) {
        float tot = part[0] + part[1] + part[2] + part[3];
        s_inv = 1.0f / fmaxf(sqrtf(tot), 1e-12f);
    }
    __syncthreads();
    float inv = s_inv;
    cbT[(size_t)(2 * t)     * KCB + k] = v.x * inv;
    cbT[(size_t)(2 * t + 1) * KCB + k] = v.y * inv;
}

// ---------------- K2: ln + attention + softmax + argmax + soft_assign + hard_quantized + partial stats
__global__ __launch_bounds__(NT) void k_attn(
    const float* __restrict__ lat, const float* __restrict__ emb,
    const float* __restrict__ cbT,
    float* __restrict__ inv_ws, float* __restrict__ avg_ws, float* __restrict__ clu_ws,
    float* __restrict__ soft_out, float* __restrict__ argm_out, float* __restrict__ hq_out)
{
    __shared__ float4 ln4[TB][D / 4];       // 32 KB, broadcast-read in the GEMM loop
    __shared__ float  s_maxp[4][TB];
    __shared__ int    s_argp[4][TB];
    __shared__ float  s_sump[4][TB];
    __shared__ float  s_rowmax[TB];
    __shared__ int    s_rowarg[TB];
    __shared__ float  s_rowinv[TB];

    const int t    = threadIdx.x;
    const int wv   = t >> 6, lane = t & 63;
    const int b0   = blockIdx.x * TB;

    // ---- Phase A: normalize 16 latent rows into LDS (wave wv handles rows 4wv..4wv+3)
    #pragma unroll
    for (int i = 0; i < 4; ++i) {
        int r = wv * 4 + i;
        int g = b0 + r;
        const float4* lp = (const float4*)(lat + (size_t)g * D);
        float4 a = lp[lane * 2], b = lp[lane * 2 + 1];
        float ss = a.x*a.x + a.y*a.y + a.z*a.z + a.w*a.w
                 + b.x*b.x + b.y*b.y + b.z*b.z + b.w*b.w;
        ss = wave_reduce_sum(ss);
        float inv = 1.0f / fmaxf(sqrtf(ss), 1e-12f);
        ln4[r][lane * 2]     = make_float4(a.x*inv, a.y*inv, a.z*inv, a.w*inv);
        ln4[r][lane * 2 + 1] = make_float4(b.x*inv, b.y*inv, b.z*inv, b.w*inv);
        if (lane == 0) inv_ws[g] = inv;
    }
    __syncthreads();

    // ---- Phase B: attention tile [16][1024]; thread t owns cols k = 4t..4t+3
    float4 acc[TB];
    #pragma unroll
    for (int r = 0; r < TB; ++r) acc[r] = make_float4(0.f, 0.f, 0.f, 0.f);
    const float4* cb4 = (const float4*)cbT;         // [d][K/4]
    for (int d4 = 0; d4 < D / 4; ++d4) {
        const int d = d4 * 4;
        float4 c0 = cb4[(size_t)(d + 0) * (KCB / 4) + t];
        float4 c1 = cb4[(size_t)(d + 1) * (KCB / 4) + t];
        float4 c2 = cb4[(size_t)(d + 2) * (KCB / 4) + t];
        float4 c3 = cb4[(size_t)(d + 3) * (KCB / 4) + t];
        #pragma unroll
        for (int r = 0; r < TB; ++r) {
            float4 L = ln4[r][d4];
            acc[r].x += L.x*c0.x + L.y*c1.x + L.z*c2.x + L.w*c3.x;
            acc[r].y += L.x*c0.y + L.y*c1.y + L.z*c2.y + L.w*c3.y;
            acc[r].z += L.x*c0.z + L.y*c1.z + L.z*c2.z + L.w*c3.z;
            acc[r].w += L.x*c0.w + L.y*c1.w + L.z*c2.w + L.w*c3.w;
        }
    }

    // ---- Phase C: row max + argmax (first-max tie-break, numpy semantics)
    float mv[TB]; int mi[TB];
    #pragma unroll
    for (int r = 0; r < TB; ++r) {
        float4 a = acc[r];
        float v = a.x; int i = 4 * t;
        if (a.y > v) { v = a.y; i = 4 * t + 1; }
        if (a.z > v) { v = a.z; i = 4 * t + 2; }
        if (a.w > v) { v = a.w; i = 4 * t + 3; }
        mv[r] = v; mi[r] = i;
    }
    #pragma unroll
    for (int r = 0; r < TB; ++r) {
        #pragma unroll
        for (int off = 32; off >= 1; off >>= 1) {
            float ov = __shfl_xor(mv[r], off, 64);
            int   oi = __shfl_xor(mi[r], off, 64);
            if (ov > mv[r] || (ov == mv[r] && oi < mi[r])) { mv[r] = ov; mi[r] = oi; }
        }
    }
    if (lane == 0) {
        #pragma unroll
        for (int r = 0; r < TB; ++r) { s_maxp[wv][r] = mv[r]; s_argp[wv][r] = mi[r]; }
    }
    __syncthreads();
    if (t < TB) {
        float v = s_maxp[0][t]; int i = s_argp[0][t];
        #pragma unroll
        for (int w = 1; w < 4; ++w) {
            float ov = s_maxp[w][t]; int oi = s_argp[w][t];
            if (ov > v || (ov == v && oi < i)) { v = ov; i = oi; }
        }
        s_rowmax[t] = v; s_rowarg[t] = i;
        argm_out[b0 + t] = (float)i;          // out buffer is read as float32
    }
    __syncthreads();

    // ---- Phase D: exp + row sums
    float sl[TB];
    #pragma unroll
    for (int r = 0; r < TB; ++r) {
        float rm = s_rowmax[r];
        float4 a = acc[r];
        a.x = __expf(ALPHA * (a.x - rm));
        a.y = __expf(ALPHA * (a.y - rm));
        a.z = __expf(ALPHA * (a.z - rm));
        a.w = __expf(ALPHA * (a.w - rm));
        acc[r] = a;
        sl[r] = a.x + a.y + a.z + a.w;
    }
    #pragma unroll
    for (int r = 0; r < TB; ++r) sl[r] = wave_reduce_sum(sl[r]);
    if (lane == 0) {
        #pragma unroll
        for (int r = 0; r < TB; ++r) s_sump[wv][r] = sl[r];
    }
    __syncthreads();
    if (t < TB) {
        float tot = s_sump[0][t] + s_sump[1][t] + s_sump[2][t] + s_sump[3][t];
        s_rowinv[t] = 1.0f / tot;
    }
    __syncthreads();

    // ---- Phase E: write soft_assign (coalesced float4), accumulate avg_probs + cluster metric
    float4 pacc = make_float4(0.f, 0.f, 0.f, 0.f);
    #pragma unroll
    for (int r = 0; r < TB; ++r) {
        float inv = s_rowinv[r];
        float4 sres = make_float4(acc[r].x * inv, acc[r].y * inv, acc[r].z * inv, acc[r].w * inv);
        ((float4*)(soft_out + (size_t)(b0 + r) * KCB))[t] = sres;
        pacc.x += sres.x; pacc.y += sres.y; pacc.z += sres.z; pacc.w += sres.w;
    }
    atomicAdd(avg_ws + 4 * t + 0, pacc.x);
    atomicAdd(avg_ws + 4 * t + 1, pacc.y);
    atomicAdd(avg_ws + 4 * t + 2, pacc.z);
    atomicAdd(avg_ws + 4 * t + 3, pacc.w);
    if (t == 0) {
        float cs = 0.f;
        #pragma unroll
        for (int r = 0; r < TB; ++r) cs += s_rowmax[r];
        atomicAdd(clu_ws, cs);
    }

    // ---- Phase F: hard_quantized = emb[argmax]
    const float4* emb4 = (const float4*)emb;
    for (int idx = t; idx < TB * (D / 4); idx += NT) {
        int r = idx >> 7;       // / (D/4)
        int c = idx & 127;
        int a = s_rowarg[r];
        ((float4*)(hq_out + (size_t)(b0 + r) * D))[c] = emb4[(size_t)a * (D / 4) + c];
    }
}

// ---------------- K3: quantized = soft_assign @ emb_weight, fused SSE((q - ln)^2)
__global__ __launch_bounds__(NT) void k_quant(
    const float* __restrict__ lat, const float* __restrict__ emb,
    const float* __restrict__ soft_in, const float* __restrict__ inv_ws,
    float* __restrict__ q_out, float* __restrict__ sse_ws)
{
    __shared__ float sft[TB][D];            // 32 KB: holds half the K range per pass
    const int t  = threadIdx.x;
    const int b0 = blockIdx.x * TB;
    float2 q[TB];
    #pragma unroll
    for (int r = 0; r < TB; ++r) q[r] = make_float2(0.f, 0.f);
    const float2* emb2 = (const float2*)emb;

    for (int p = 0; p < 2; ++p) {
        const float4* s4 = (const float4*)soft_in;
        for (int idx = t; idx < TB * 128; idx += NT) {
            int r = idx >> 7, c = idx & 127;
            ((float4*)&sft[r][0])[c] = s4[(size_t)(b0 + r) * (KCB / 4) + p * 128 + c];
        }
        __syncthreads();
        const int kbase = p * 512;
        for (int kk = 0; kk < 512; kk += 2) {
            float2 w0 = emb2[(size_t)(kbase + kk)     * (D / 2) + t];   // d = 2t, 2t+1
            float2 w1 = emb2[(size_t)(kbase + kk + 1) * (D / 2) + t];
            #pragma unroll
            for (int r = 0; r < TB; ++r) {
                float2 sv = *(const float2*)&sft[r][kk];
                q[r].x += sv.x * w0.x + sv.y * w1.x;
                q[r].y += sv.x * w0.y + sv.y * w1.y;
            }
        }
        __syncthreads();
    }

    const float2* lat2 = (const float2*)lat;
    float sse = 0.f;
    #pragma unroll
    for (int r = 0; r < TB; ++r) {
        int g = b0 + r;
        float inv = inv_ws[g];
        float2 lv = lat2[(size_t)g * (D / 2) + t];
        float dx = q[r].x - lv.x * inv;
        float dy = q[r].y - lv.y * inv;
        sse += dx * dx + dy * dy;
        ((float2*)(q_out + (size_t)g * D))[t] = q[r];
    }
    sse = wave_reduce_sum(sse);
    __shared__ float part[4];
    const int wv = t >> 6, lane = t & 63;
    if (lane == 0) part[wv] = sse;
    __syncthreads();
    if (t == 0) atomicAdd(sse_ws, part[0] + part[1] + part[2] + part[3]);
}

// ---------------- K4: scalars (vq_loss, entropy, cluster_metric)
__global__ __launch_bounds__(NT) void k_final(
    const float* __restrict__ avg_ws, const float* __restrict__ sse_ws, const float* __restrict__ clu_ws,
    float* __restrict__ out_vq, float* __restrict__ out_ent, float* __restrict__ out_cm,
    float invB, float invBD)
{
    const int t = threadIdx.x;
    float ent = 0.f;
    for (int idx = t; idx < KCB; idx += NT) {
        float pv = avg_ws[idx] * invB;
        ent -= pv * logf(pv + 1e-10f);
    }
    ent = wave_reduce_sum(ent);
    __shared__ float part[4];
    const int wv = t >> 6, lane = t & 63;
    if (lane == 0) part[wv] = ent;
    __syncthreads();
    if (t == 0) {
        *out_ent = part[0] + part[1] + part[2] + part[3];
        *out_vq  = 1.25f * (*sse_ws) * invBD;     // (BETA + 1) * MSE
        *out_cm  = (*clu_ws) * invB;
    }
}

extern "C" void kernel_launch(void* const* d_in, const int* in_sizes, int n_in,
                              void* d_out, int out_size, void* d_ws, size_t ws_size,
                              hipStream_t stream)
{
    const float* lat = (const float*)d_in[0];
    const float* emb = (const float*)d_in[1];
    const int B = in_sizes[0] / D;           // 16384
    float* out = (float*)d_out;

    // output layout: quantized | vq_loss | entropy | argm | hard_quantized | soft_assign | cluster_metric
    const size_t vq_off   = (size_t)B * D;
    const size_t ent_off  = vq_off + 1;
    const size_t argm_off = vq_off + 2;
    const size_t hq_off   = argm_off + (size_t)B;
    const size_t soft_off = hq_off + (size_t)B * D;
    const size_t cm_off   = soft_off + (size_t)B * KCB;

    float* ws     = (float*)d_ws;
    float* cbT    = ws;                          // D*K floats (2 MB)
    float* inv_ws = ws + (size_t)D * KCB;        // B floats
    float* avg_ws = inv_ws + B;                  // K floats
    float* sse_ws = avg_ws + KCB;                // 1
    float* clu_ws = sse_ws + 1;                  // 1

    k_init<<<4, NT, 0, stream>>>(avg_ws, sse_ws, clu_ws);
    k_cbt<<<KCB, NT, 0, stream>>>(emb, cbT);
    k_attn<<<B / TB, NT, 0, stream>>>(lat, emb, cbT, inv_ws, avg_ws, clu_ws,
                                      out + soft_off, out + argm_off, out + hq_off);
    k_quant<<<B / TB, NT, 0, stream>>>(lat, emb, out + soft_off, inv_ws, out, sse_ws);
    k_final<<<1, NT, 0, stream>>>(avg_ws, sse_ws, clu_ws,
                                  out + vq_off, out + ent_off, out + cm_off,
                                  1.0f / (float)B, 1.0f / ((float)B * (float)D));
}

// Round 2
// 362.000 us; speedup vs baseline: 2.1537x; 2.1537x over previous
//
#include <hip/hip_runtime.h>
#include <math.h>

#define D     512
#define KCB   1024
#define NT    256
#define ALPHA 10.0f
#define TAU   0.008f

typedef __attribute__((ext_vector_type(8))) short short8v;
typedef __attribute__((ext_vector_type(4))) float f32x4;
typedef unsigned short us;

__device__ __forceinline__ float wave_reduce_sum(float v) {
    #pragma unroll
    for (int off = 32; off >= 1; off >>= 1) v += __shfl_xor(v, off, 64);
    return v;
}

// fp32 -> bf16 round-to-nearest-even
__device__ __forceinline__ short bf16r(float x) {
    union { float f; unsigned u; } c; c.f = x;
    unsigned r = (c.u + 0x7FFFu + ((c.u >> 16) & 1u)) >> 16;
    return (short)r;
}

// ---------------- K0: zero ws accumulators (ws poisoned each call)
__global__ void k_init(float* __restrict__ avg, float* __restrict__ sse, float* __restrict__ clu) {
    int t = threadIdx.x + blockIdx.x * blockDim.x;
    if (t < KCB) avg[t] = 0.0f;
    if (t == 0) { *sse = 0.0f; *clu = 0.0f; }
}

// ---------------- K1: normalized codebook in bf16, row-major [k][d]; plus 1/||emb_k||
__global__ __launch_bounds__(NT) void k_prep(const float* __restrict__ emb,
                                             us* __restrict__ cb, float* __restrict__ cbinv) {
    const int k = blockIdx.x, t = threadIdx.x;
    const int wv = t >> 6, lane = t & 63;
    float2 v = ((const float2*)(emb + (size_t)k * D))[t];
    float ss = wave_reduce_sum(v.x * v.x + v.y * v.y);
    __shared__ float part[4];
    __shared__ float s_i;
    if (lane == 0) part[wv] = ss;
    __syncthreads();
    if (t == 0) s_i = 1.0f / fmaxf(sqrtf(part[0] + part[1] + part[2] + part[3]), 1e-12f);
    __syncthreads();
    float inv = s_i;
    unsigned lo = (unsigned short)bf16r(v.x * inv);
    unsigned hi = (unsigned short)bf16r(v.y * inv);
    ((unsigned*)(cb + (size_t)k * D))[t] = lo | (hi << 16);
    if (t == 0) cbinv[k] = inv;
}

// ---------------- K1b: embT_bf16[d][k] = bf16(emb[k][d])  (B-operand for k_quant)
__global__ __launch_bounds__(NT) void k_tr(const float* __restrict__ emb, us* __restrict__ embT) {
    __shared__ us tile[64][65];
    const int t = threadIdx.x;
    const int k0 = (blockIdx.x & 15) * 64;
    const int d0 = (blockIdx.x >> 4) * 64;
    {
        const int r = t >> 2, cq = t & 3;
        const float4* ep = (const float4*)(emb + (size_t)(k0 + r) * D + d0 + cq * 16);
        float4 v0 = ep[0], v1 = ep[1], v2 = ep[2], v3 = ep[3];
        us* tp = &tile[r][cq * 16];
        tp[0] = (us)bf16r(v0.x); tp[1] = (us)bf16r(v0.y); tp[2] = (us)bf16r(v0.z); tp[3] = (us)bf16r(v0.w);
        tp[4] = (us)bf16r(v1.x); tp[5] = (us)bf16r(v1.y); tp[6] = (us)bf16r(v1.z); tp[7] = (us)bf16r(v1.w);
        tp[8] = (us)bf16r(v2.x); tp[9] = (us)bf16r(v2.y); tp[10] = (us)bf16r(v2.z); tp[11] = (us)bf16r(v2.w);
        tp[12] = (us)bf16r(v3.x); tp[13] = (us)bf16r(v3.y); tp[14] = (us)bf16r(v3.z); tp[15] = (us)bf16r(v3.w);
    }
    __syncthreads();
    {
        const int rd = t >> 2, kq = t & 3;
        short8v w0, w1;
        #pragma unroll
        for (int j = 0; j < 8; ++j) w0[j] = (short)tile[kq * 16 + j][rd];
        #pragma unroll
        for (int j = 0; j < 8; ++j) w1[j] = (short)tile[kq * 16 + 8 + j][rd];
        us* op = embT + (size_t)(d0 + rd) * KCB + k0 + kq * 16;
        *(short8v*)op = w0;
        *((short8v*)op + 1) = w1;
    }
}

// ---------------- K2: MFMA attention + softmax + fp32-rescued argmax + stats
// Block: 32 latent rows, 4 waves, wave wv owns cols [256wv, 256wv+256).
__global__ __launch_bounds__(NT, 2) void k_attn(
    const float* __restrict__ lat, const float* __restrict__ emb,
    const us* __restrict__ cb, const float* __restrict__ cbinv,
    float* __restrict__ inv_ws, float* __restrict__ avg_ws, float* __restrict__ clu_ws,
    float* __restrict__ soft_out, float* __restrict__ argm_out, float* __restrict__ hq_out)
{
    __shared__ float s_inv[32];
    __shared__ float s_maxp[4][32];
    __shared__ float s_amax[32];
    __shared__ float s_sump[4][32];
    __shared__ float s_den[32];
    __shared__ float s_bestv[32];
    __shared__ int   s_besti[32];
    __shared__ int   s_cnt;
    __shared__ int   s_ck[512];
    __shared__ float s_cv[512];

    const int t = threadIdx.x, wv = t >> 6, lane = t & 63;
    const int q15 = lane & 15, g = lane >> 4;
    const int b0 = blockIdx.x * 32;

    // ---- Phase A: inverse norms for the block's 32 rows (wave wv -> rows 8wv..8wv+7)
    for (int i = 0; i < 8; ++i) {
        int r = wv * 8 + i, grow = b0 + r;
        const float4* lp = (const float4*)(lat + (size_t)grow * D);
        float4 a = lp[2 * lane], b = lp[2 * lane + 1];
        float ss = a.x*a.x + a.y*a.y + a.z*a.z + a.w*a.w
                 + b.x*b.x + b.y*b.y + b.z*b.z + b.w*b.w;
        ss = wave_reduce_sum(ss);
        float inv = 1.0f / fmaxf(sqrtf(ss), 1e-12f);
        if (lane == 0) { s_inv[r] = inv; inv_ws[grow] = inv; }
    }
    if (t == 0) s_cnt = 0;
    __syncthreads();

    // ---- Phase B: MFMA GEMM. A = bf16(lat*inv) on the fly; B = cb (bf16, L2-resident).
    f32x4 acc[2][16];
    #pragma unroll
    for (int m = 0; m < 2; ++m)
        #pragma unroll
        for (int ct = 0; ct < 16; ++ct) { f32x4 z = {0.f, 0.f, 0.f, 0.f}; acc[m][ct] = z; }

    const float inv0 = s_inv[q15], inv1 = s_inv[16 + q15];
    const float* pA0 = lat + (size_t)(b0 + q15) * D + g * 8;
    const float* pA1 = lat + (size_t)(b0 + 16 + q15) * D + g * 8;
    const us*    pB  = cb  + (size_t)(wv * 256 + q15) * D + g * 8;

    for (int ks = 0; ks < 16; ++ks) {
        float4 a0 = *(const float4*)(pA0 + ks * 32);
        float4 a1 = *(const float4*)(pA0 + ks * 32 + 4);
        float4 c0 = *(const float4*)(pA1 + ks * 32);
        float4 c1 = *(const float4*)(pA1 + ks * 32 + 4);
        short8v af0, af1;
        af0[0] = bf16r(a0.x * inv0); af0[1] = bf16r(a0.y * inv0);
        af0[2] = bf16r(a0.z * inv0); af0[3] = bf16r(a0.w * inv0);
        af0[4] = bf16r(a1.x * inv0); af0[5] = bf16r(a1.y * inv0);
        af0[6] = bf16r(a1.z * inv0); af0[7] = bf16r(a1.w * inv0);
        af1[0] = bf16r(c0.x * inv1); af1[1] = bf16r(c0.y * inv1);
        af1[2] = bf16r(c0.z * inv1); af1[3] = bf16r(c0.w * inv1);
        af1[4] = bf16r(c1.x * inv1); af1[5] = bf16r(c1.y * inv1);
        af1[6] = bf16r(c1.z * inv1); af1[7] = bf16r(c1.w * inv1);
        #pragma unroll
        for (int ct = 0; ct < 16; ++ct) {
            short8v bf = *(const short8v*)(pB + (size_t)ct * 16 * D + ks * 32);
            acc[0][ct] = __builtin_amdgcn_mfma_f32_16x16x32_bf16(af0, bf, acc[0][ct], 0, 0, 0);
            acc[1][ct] = __builtin_amdgcn_mfma_f32_16x16x32_bf16(af1, bf, acc[1][ct], 0, 0, 0);
        }
    }
    // lane holds: rows (block-local) 16m + 4g + i, cols 256wv + 16ct + q15

    // ---- Phase C: approx row max (cross-lane over q15 within group, then cross-wave)
    #pragma unroll
    for (int m = 0; m < 2; ++m)
        #pragma unroll
        for (int i = 0; i < 4; ++i) {
            float v = acc[m][0][i];
            #pragma unroll
            for (int ct = 1; ct < 16; ++ct) v = fmaxf(v, acc[m][ct][i]);
            #pragma unroll
            for (int off = 8; off >= 1; off >>= 1) v = fmaxf(v, __shfl_xor(v, off, 64));
            if (q15 == 0) s_maxp[wv][m * 16 + g * 4 + i] = v;
        }
    __syncthreads();
    if (t < 32)
        s_amax[t] = fmaxf(fmaxf(s_maxp[0][t], s_maxp[1][t]), fmaxf(s_maxp[2][t], s_maxp[3][t]));
    __syncthreads();

    // ---- Phase C2: candidate gather (approx score within TAU of approx max)
    #pragma unroll
    for (int m = 0; m < 2; ++m)
        #pragma unroll
        for (int i = 0; i < 4; ++i) {
            const int row = m * 16 + g * 4 + i;
            const float thr = s_amax[row] - TAU;
            #pragma unroll
            for (int ct = 0; ct < 16; ++ct) {
                if (acc[m][ct][i] >= thr) {
                    int idx = atomicAdd(&s_cnt, 1);
                    if (idx < 512) s_ck[idx] = (row << 16) | (wv * 256 + ct * 16 + q15);
                }
            }
        }
    __syncthreads();
    const int cnt = (s_cnt < 512) ? s_cnt : 512;

    // ---- Phase C3: fp32 rescue — exact dot for each candidate (wave-parallel over d)
    for (int e = wv; e < cnt; e += 4) {
        const int pk = s_ck[e];
        const int row = pk >> 16, kk = pk & 0xFFFF;
        const float4* lp = (const float4*)(lat + (size_t)(b0 + row) * D);
        const float4* ep = (const float4*)(emb + (size_t)kk * D);
        float4 x0 = lp[2 * lane], x1 = lp[2 * lane + 1];
        float4 y0 = ep[2 * lane], y1 = ep[2 * lane + 1];
        float dp = x0.x*y0.x + x0.y*y0.y + x0.z*y0.z + x0.w*y0.w
                 + x1.x*y1.x + x1.y*y1.y + x1.z*y1.z + x1.w*y1.w;
        dp = wave_reduce_sum(dp);
        if (lane == 0) s_cv[e] = dp * s_inv[row] * cbinv[kk];
    }
    __syncthreads();
    if (t < 32) {
        float bv = -1e30f; int bi = 0x7FFFFFFF;
        for (int e = 0; e < cnt; ++e) {
            if ((s_ck[e] >> 16) == t) {
                float v = s_cv[e]; int kk = s_ck[e] & 0xFFFF;
                if (v > bv || (v == bv && kk < bi)) { bv = v; bi = kk; }
            }
        }
        s_bestv[t] = bv; s_besti[t] = bi;
        argm_out[b0 + t] = (float)bi;
    }
    __syncthreads();

    // ---- Phase D: exp + row sums
    #pragma unroll
    for (int m = 0; m < 2; ++m)
        #pragma unroll
        for (int i = 0; i < 4; ++i) {
            const float bvv = s_bestv[m * 16 + g * 4 + i];
            float s = 0.f;
            #pragma unroll
            for (int ct = 0; ct < 16; ++ct) {
                float e = __expf(ALPHA * (acc[m][ct][i] - bvv));
                acc[m][ct][i] = e;
                s += e;
            }
            #pragma unroll
            for (int off = 8; off >= 1; off >>= 1) s += __shfl_xor(s, off, 64);
            if (q15 == 0) s_sump[wv][m * 16 + g * 4 + i] = s;
        }
    __syncthreads();
    if (t < 32) s_den[t] = 1.0f / (s_sump[0][t] + s_sump[1][t] + s_sump[2][t] + s_sump[3][t]);
    __syncthreads();

    // ---- Phase E: soft_assign store + avg_probs partials + cluster metric
    float csum[16];
    #pragma unroll
    for (int ct = 0; ct < 16; ++ct) csum[ct] = 0.f;
    #pragma unroll
    for (int m = 0; m < 2; ++m)
        #pragma unroll
        for (int i = 0; i < 4; ++i) {
            const int row = m * 16 + g * 4 + i;
            const float dn = s_den[row];
            float* orow = soft_out + (size_t)(b0 + row) * KCB + wv * 256 + q15;
            #pragma unroll
            for (int ct = 0; ct < 16; ++ct) {
                float sv = acc[m][ct][i] * dn;
                orow[ct * 16] = sv;
                csum[ct] += sv;
            }
        }
    #pragma unroll
    for (int ct = 0; ct < 16; ++ct) {
        float v = csum[ct];
        v += __shfl_xor(v, 16, 64);
        v += __shfl_xor(v, 32, 64);
        csum[ct] = v;
    }
    if (lane < 16) {
        #pragma unroll
        for (int ct = 0; ct < 16; ++ct)
            atomicAdd(avg_ws + wv * 256 + ct * 16 + lane, csum[ct]);
    }
    if (t == 0) {
        float cs = 0.f;
        #pragma unroll
        for (int r = 0; r < 32; ++r) cs += s_bestv[r];
        atomicAdd(clu_ws, cs);
    }

    // ---- Phase F: hard_quantized = emb[argmax]
    const float4* emb4 = (const float4*)emb;
    for (int idx = t; idx < 32 * 128; idx += NT) {
        int r = idx >> 7, c = idx & 127;
        ((float4*)(hq_out + (size_t)(b0 + r) * D))[c] = emb4[(size_t)s_besti[r] * 128 + c];
    }
}

// ---------------- K3: MFMA quantized = soft @ emb (embT bf16), fused SSE
// Block: 32 rows, 4 waves, wave wv owns d-cols [128wv, 128wv+128).
__global__ __launch_bounds__(NT, 2) void k_quant(
    const float* __restrict__ lat, const us* __restrict__ embT,
    const float* __restrict__ soft_in, const float* __restrict__ inv_ws,
    float* __restrict__ q_out, float* __restrict__ sse_ws)
{
    const int t = threadIdx.x, wv = t >> 6, lane = t & 63;
    const int q15 = lane & 15, g = lane >> 4;
    const int b0 = blockIdx.x * 32;

    f32x4 acc[2][8];
    #pragma unroll
    for (int m = 0; m < 2; ++m)
        #pragma unroll
        for (int ct = 0; ct < 8; ++ct) { f32x4 z = {0.f, 0.f, 0.f, 0.f}; acc[m][ct] = z; }

    const float* pA0 = soft_in + (size_t)(b0 + q15) * KCB + g * 8;
    const float* pA1 = soft_in + (size_t)(b0 + 16 + q15) * KCB + g * 8;
    const us*    pB  = embT + (size_t)(wv * 128 + q15) * KCB + g * 8;

    for (int ks = 0; ks < 32; ++ks) {
        float4 a0 = *(const float4*)(pA0 + ks * 32);
        float4 a1 = *(const float4*)(pA0 + ks * 32 + 4);
        float4 c0 = *(const float4*)(pA1 + ks * 32);
        float4 c1 = *(const float4*)(pA1 + ks * 32 + 4);
        short8v af0, af1;
        af0[0] = bf16r(a0.x); af0[1] = bf16r(a0.y); af0[2] = bf16r(a0.z); af0[3] = bf16r(a0.w);
        af0[4] = bf16r(a1.x); af0[5] = bf16r(a1.y); af0[6] = bf16r(a1.z); af0[7] = bf16r(a1.w);
        af1[0] = bf16r(c0.x); af1[1] = bf16r(c0.y); af1[2] = bf16r(c0.z); af1[3] = bf16r(c0.w);
        af1[4] = bf16r(c1.x); af1[5] = bf16r(c1.y); af1[6] = bf16r(c1.z); af1[7] = bf16r(c1.w);
        #pragma unroll
        for (int ct = 0; ct < 8; ++ct) {
            short8v bf = *(const short8v*)(pB + (size_t)ct * 16 * KCB + ks * 32);
            acc[0][ct] = __builtin_amdgcn_mfma_f32_16x16x32_bf16(af0, bf, acc[0][ct], 0, 0, 0);
            acc[1][ct] = __builtin_amdgcn_mfma_f32_16x16x32_bf16(af1, bf, acc[1][ct], 0, 0, 0);
        }
    }

    float rv[2][4];
    #pragma unroll
    for (int m = 0; m < 2; ++m)
        #pragma unroll
        for (int i = 0; i < 4; ++i) rv[m][i] = inv_ws[b0 + m * 16 + g * 4 + i];

    float sse = 0.f;
    #pragma unroll
    for (int m = 0; m < 2; ++m)
        #pragma unroll
        for (int i = 0; i < 4; ++i) {
            const int row = b0 + m * 16 + g * 4 + i;
            const float* lrow = lat + (size_t)row * D + wv * 128 + q15;
            float* qrow = q_out + (size_t)row * D + wv * 128 + q15;
            #pragma unroll
            for (int ct = 0; ct < 8; ++ct) {
                float qv = acc[m][ct][i];
                qrow[ct * 16] = qv;
                float df = qv - lrow[ct * 16] * rv[m][i];
                sse += df * df;
            }
        }
    sse = wave_reduce_sum(sse);
    __shared__ float part[4];
    if (lane == 0) part[wv] = sse;
    __syncthreads();
    if (t == 0) atomicAdd(sse_ws, part[0] + part[1] + part[2] + part[3]);
}

// ---------------- K4: scalars
__global__ __launch_bounds__(NT) void k_final(
    const float* __restrict__ avg_ws, const float* __restrict__ sse_ws, const float* __restrict__ clu_ws,
    float* __restrict__ out_vq, float* __restrict__ out_ent, float* __restrict__ out_cm,
    float invB, float invBD)
{
    const int t = threadIdx.x;
    float ent = 0.f;
    for (int idx = t; idx < KCB; idx += NT) {
        float pv = avg_ws[idx] * invB;
        ent -= pv * logf(pv + 1e-10f);
    }
    ent = wave_reduce_sum(ent);
    __shared__ float part[4];
    const int wv = t >> 6, lane = t & 63;
    if (lane == 0) part[wv] = ent;
    __syncthreads();
    if (t == 0) {
        *out_ent = part[0] + part[1] + part[2] + part[3];
        *out_vq  = 1.25f * (*sse_ws) * invBD;
        *out_cm  = (*clu_ws) * invB;
    }
}

extern "C" void kernel_launch(void* const* d_in, const int* in_sizes, int n_in,
                              void* d_out, int out_size, void* d_ws, size_t ws_size,
                              hipStream_t stream)
{
    const float* lat = (const float*)d_in[0];
    const float* emb = (const float*)d_in[1];
    const int B = in_sizes[0] / D;           // 16384
    float* out = (float*)d_out;

    const size_t vq_off   = (size_t)B * D;
    const size_t ent_off  = vq_off + 1;
    const size_t argm_off = vq_off + 2;
    const size_t hq_off   = argm_off + (size_t)B;
    const size_t soft_off = hq_off + (size_t)B * D;
    const size_t cm_off   = soft_off + (size_t)B * KCB;

    us* cb_bf   = (us*)d_ws;                          // K*D bf16 (1 MB)
    us* embT_bf = cb_bf + (size_t)KCB * D;            // D*K bf16 (1 MB)
    float* fbase  = (float*)(embT_bf + (size_t)D * KCB);
    float* inv_ws = fbase;                            // B floats
    float* cbinv  = inv_ws + B;                       // K floats
    float* avg_ws = cbinv + KCB;                      // K floats
    float* sse_ws = avg_ws + KCB;                     // 1
    float* clu_ws = sse_ws + 1;                       // 1

    k_init<<<4, NT, 0, stream>>>(avg_ws, sse_ws, clu_ws);
    k_prep<<<KCB, NT, 0, stream>>>(emb, cb_bf, cbinv);
    k_tr<<<(D / 64) * (KCB / 64), NT, 0, stream>>>(emb, embT_bf);
    k_attn<<<B / 32, NT, 0, stream>>>(lat, emb, cb_bf, cbinv, inv_ws, avg_ws, clu_ws,
                                      out + soft_off, out + argm_off, out + hq_off);
    k_quant<<<B / 32, NT, 0, stream>>>(lat, embT_bf, out + soft_off, inv_ws, out, sse_ws);
    k_final<<<1, NT, 0, stream>>>(avg_ws, sse_ws, clu_ws,
                                  out + vq_off, out + ent_off, out + cm_off,
                                  1.0f / (float)B, 1.0f / ((float)B * (float)D));
}

// Round 3
// 317.998 us; speedup vs baseline: 2.4518x; 1.1384x over previous
//
#include <hip/hip_runtime.h>
#include <math.h>

#define D     512
#define KCB   1024
#define NT    256
#define NT2   512
#define ALPHA 10.0f
#define TAU   0.008f

typedef __attribute__((ext_vector_type(8))) short short8v;
typedef __attribute__((ext_vector_type(4))) float f32x4;
typedef unsigned short us;

__device__ __forceinline__ float wave_reduce_sum(float v) {
    #pragma unroll
    for (int off = 32; off >= 1; off >>= 1) v += __shfl_xor(v, off, 64);
    return v;
}

// fp32 -> bf16 round-to-nearest-even
__device__ __forceinline__ short bf16r(float x) {
    union { float f; unsigned u; } c; c.f = x;
    unsigned r = (c.u + 0x7FFFu + ((c.u >> 16) & 1u)) >> 16;
    return (short)r;
}

// ---------------- K0: zero ws accumulators (ws poisoned each call)
__global__ void k_init(float* __restrict__ avg, float* __restrict__ sse, float* __restrict__ clu) {
    int t = threadIdx.x + blockIdx.x * blockDim.x;
    if (t < KCB) avg[t] = 0.0f;
    if (t == 0) { *sse = 0.0f; *clu = 0.0f; }
}

// ---------------- K1: normalized codebook in bf16, row-major [k][d]; plus 1/||emb_k||
__global__ __launch_bounds__(NT) void k_prep(const float* __restrict__ emb,
                                             us* __restrict__ cb, float* __restrict__ cbinv) {
    const int k = blockIdx.x, t = threadIdx.x;
    const int wv = t >> 6, lane = t & 63;
    float2 v = ((const float2*)(emb + (size_t)k * D))[t];
    float ss = wave_reduce_sum(v.x * v.x + v.y * v.y);
    __shared__ float part[4];
    __shared__ float s_i;
    if (lane == 0) part[wv] = ss;
    __syncthreads();
    if (t == 0) s_i = 1.0f / fmaxf(sqrtf(part[0] + part[1] + part[2] + part[3]), 1e-12f);
    __syncthreads();
    float inv = s_i;
    unsigned lo = (unsigned short)bf16r(v.x * inv);
    unsigned hi = (unsigned short)bf16r(v.y * inv);
    ((unsigned*)(cb + (size_t)k * D))[t] = lo | (hi << 16);
    if (t == 0) cbinv[k] = inv;
}

// ---------------- K1b: embT_bf16[d][k] = bf16(emb[k][d])  (B-operand for k_quant)
__global__ __launch_bounds__(NT) void k_tr(const float* __restrict__ emb, us* __restrict__ embT) {
    __shared__ us tile[64][65];
    const int t = threadIdx.x;
    const int k0 = (blockIdx.x & 15) * 64;
    const int d0 = (blockIdx.x >> 4) * 64;
    {
        const int r = t >> 2, cq = t & 3;
        const float4* ep = (const float4*)(emb + (size_t)(k0 + r) * D + d0 + cq * 16);
        float4 v0 = ep[0], v1 = ep[1], v2 = ep[2], v3 = ep[3];
        us* tp = &tile[r][cq * 16];
        tp[0] = (us)bf16r(v0.x); tp[1] = (us)bf16r(v0.y); tp[2] = (us)bf16r(v0.z); tp[3] = (us)bf16r(v0.w);
        tp[4] = (us)bf16r(v1.x); tp[5] = (us)bf16r(v1.y); tp[6] = (us)bf16r(v1.z); tp[7] = (us)bf16r(v1.w);
        tp[8] = (us)bf16r(v2.x); tp[9] = (us)bf16r(v2.y); tp[10] = (us)bf16r(v2.z); tp[11] = (us)bf16r(v2.w);
        tp[12] = (us)bf16r(v3.x); tp[13] = (us)bf16r(v3.y); tp[14] = (us)bf16r(v3.z); tp[15] = (us)bf16r(v3.w);
    }
    __syncthreads();
    {
        const int rd = t >> 2, kq = t & 3;
        short8v w0, w1;
        #pragma unroll
        for (int j = 0; j < 8; ++j) w0[j] = (short)tile[kq * 16 + j][rd];
        #pragma unroll
        for (int j = 0; j < 8; ++j) w1[j] = (short)tile[kq * 16 + 8 + j][rd];
        us* op = embT + (size_t)(d0 + rd) * KCB + k0 + kq * 16;
        *(short8v*)op = w0;
        *((short8v*)op + 1) = w1;
    }
}

// ---------------- K2: MFMA attention + softmax + fp32-rescued argmax + stats
// Block: 32 latent rows, 8 waves, wave wv owns cols [128wv, 128wv+128).
__global__ __launch_bounds__(NT2, 3) void k_attn(
    const float* __restrict__ lat, const float* __restrict__ emb,
    const us* __restrict__ cb, const float* __restrict__ cbinv,
    float* __restrict__ inv_ws, float* __restrict__ avg_ws, float* __restrict__ clu_ws,
    float* __restrict__ soft_out, float* __restrict__ argm_out, float* __restrict__ hq_out)
{
    __shared__ __align__(16) us alds[32][520];   // bf16 normalized A, padded stride
    __shared__ float s_inv[32];
    __shared__ float s_maxp[8][32];
    __shared__ float s_amax[32];
    __shared__ float s_sump[8][32];
    __shared__ float s_den[32];
    __shared__ float s_bestv[32];
    __shared__ int   s_besti[32];
    __shared__ int   s_cnt;
    __shared__ int   s_ck[512];
    __shared__ float s_cv[512];

    const int t = threadIdx.x, wv = t >> 6, lane = t & 63;
    const int q15 = lane & 15, g = lane >> 4;
    const int b0 = blockIdx.x * 32;

    // ---- Phase A: normalize 32 rows (4 per wave), store bf16 into LDS
    #pragma unroll
    for (int i = 0; i < 4; ++i) {
        int r = wv * 4 + i, grow = b0 + r;
        const float4* lp = (const float4*)(lat + (size_t)grow * D);
        float4 a = lp[2 * lane], b = lp[2 * lane + 1];
        float ss = a.x*a.x + a.y*a.y + a.z*a.z + a.w*a.w
                 + b.x*b.x + b.y*b.y + b.z*b.z + b.w*b.w;
        ss = wave_reduce_sum(ss);
        float inv = 1.0f / fmaxf(sqrtf(ss), 1e-12f);
        short8v w;
        w[0] = bf16r(a.x * inv); w[1] = bf16r(a.y * inv);
        w[2] = bf16r(a.z * inv); w[3] = bf16r(a.w * inv);
        w[4] = bf16r(b.x * inv); w[5] = bf16r(b.y * inv);
        w[6] = bf16r(b.z * inv); w[7] = bf16r(b.w * inv);
        *(short8v*)&alds[r][lane * 8] = w;
        if (lane == 0) { s_inv[r] = inv; inv_ws[grow] = inv; }
    }
    if (t == 0) s_cnt = 0;
    __syncthreads();

    // ---- Phase B: MFMA GEMM. A from LDS (bf16), B = cb (bf16, L2-resident).
    f32x4 acc[2][8];
    #pragma unroll
    for (int m = 0; m < 2; ++m)
        #pragma unroll
        for (int ct = 0; ct < 8; ++ct) { f32x4 z = {0.f, 0.f, 0.f, 0.f}; acc[m][ct] = z; }

    const us* pB = cb + (size_t)(wv * 128 + q15) * D;
    for (int ks = 0; ks < 16; ++ks) {
        short8v af0 = *(const short8v*)&alds[q15][ks * 32 + g * 8];
        short8v af1 = *(const short8v*)&alds[16 + q15][ks * 32 + g * 8];
        short8v bfr[8];
        #pragma unroll
        for (int ct = 0; ct < 8; ++ct)
            bfr[ct] = *(const short8v*)(pB + (size_t)ct * 16 * D + ks * 32 + g * 8);
        #pragma unroll
        for (int ct = 0; ct < 8; ++ct) {
            acc[0][ct] = __builtin_amdgcn_mfma_f32_16x16x32_bf16(af0, bfr[ct], acc[0][ct], 0, 0, 0);
            acc[1][ct] = __builtin_amdgcn_mfma_f32_16x16x32_bf16(af1, bfr[ct], acc[1][ct], 0, 0, 0);
        }
    }
    // lane holds: rows (block-local) 16m + 4g + i, cols 128wv + 16ct + q15

    // ---- Phase C: approx row max
    #pragma unroll
    for (int m = 0; m < 2; ++m)
        #pragma unroll
        for (int i = 0; i < 4; ++i) {
            float v = acc[m][0][i];
            #pragma unroll
            for (int ct = 1; ct < 8; ++ct) v = fmaxf(v, acc[m][ct][i]);
            #pragma unroll
            for (int off = 8; off >= 1; off >>= 1) v = fmaxf(v, __shfl_xor(v, off, 64));
            if (q15 == 0) s_maxp[wv][m * 16 + g * 4 + i] = v;
        }
    __syncthreads();
    if (t < 32) {
        float v = s_maxp[0][t];
        #pragma unroll
        for (int w = 1; w < 8; ++w) v = fmaxf(v, s_maxp[w][t]);
        s_amax[t] = v;
    }
    __syncthreads();

    // ---- Phase C2: candidate gather (approx score within TAU of approx max)
    #pragma unroll
    for (int m = 0; m < 2; ++m)
        #pragma unroll
        for (int i = 0; i < 4; ++i) {
            const int row = m * 16 + g * 4 + i;
            const float thr = s_amax[row] - TAU;
            #pragma unroll
            for (int ct = 0; ct < 8; ++ct) {
                if (acc[m][ct][i] >= thr) {
                    int idx = atomicAdd(&s_cnt, 1);
                    if (idx < 512) s_ck[idx] = (row << 16) | (wv * 128 + ct * 16 + q15);
                }
            }
        }
    __syncthreads();
    const int cnt = (s_cnt < 512) ? s_cnt : 512;

    // ---- Phase C3: fp32 rescue — exact dot for each candidate (wave-parallel over d)
    for (int e = wv; e < cnt; e += 8) {
        const int pk = s_ck[e];
        const int row = pk >> 16, kk = pk & 0xFFFF;
        const float4* lp = (const float4*)(lat + (size_t)(b0 + row) * D);
        const float4* ep = (const float4*)(emb + (size_t)kk * D);
        float4 x0 = lp[2 * lane], x1 = lp[2 * lane + 1];
        float4 y0 = ep[2 * lane], y1 = ep[2 * lane + 1];
        float dp = x0.x*y0.x + x0.y*y0.y + x0.z*y0.z + x0.w*y0.w
                 + x1.x*y1.x + x1.y*y1.y + x1.z*y1.z + x1.w*y1.w;
        dp = wave_reduce_sum(dp);
        if (lane == 0) s_cv[e] = dp * s_inv[row] * cbinv[kk];
    }
    __syncthreads();
    if (t < 32) {
        float bv = -1e30f; int bi = 0x7FFFFFFF;
        for (int e = 0; e < cnt; ++e) {
            if ((s_ck[e] >> 16) == t) {
                float v = s_cv[e]; int kk = s_ck[e] & 0xFFFF;
                if (v > bv || (v == bv && kk < bi)) { bv = v; bi = kk; }
            }
        }
        s_bestv[t] = bv; s_besti[t] = bi;
        argm_out[b0 + t] = (float)bi;
    }
    __syncthreads();

    // ---- Phase D: exp + row sums
    #pragma unroll
    for (int m = 0; m < 2; ++m)
        #pragma unroll
        for (int i = 0; i < 4; ++i) {
            const float bvv = s_bestv[m * 16 + g * 4 + i];
            float s = 0.f;
            #pragma unroll
            for (int ct = 0; ct < 8; ++ct) {
                float e = __expf(ALPHA * (acc[m][ct][i] - bvv));
                acc[m][ct][i] = e;
                s += e;
            }
            #pragma unroll
            for (int off = 8; off >= 1; off >>= 1) s += __shfl_xor(s, off, 64);
            if (q15 == 0) s_sump[wv][m * 16 + g * 4 + i] = s;
        }
    __syncthreads();
    if (t < 32) {
        float s = s_sump[0][t];
        #pragma unroll
        for (int w = 1; w < 8; ++w) s += s_sump[w][t];
        s_den[t] = 1.0f / s;
    }
    __syncthreads();

    // ---- Phase E: soft_assign store + avg_probs partials + cluster metric
    float csum[8];
    #pragma unroll
    for (int ct = 0; ct < 8; ++ct) csum[ct] = 0.f;
    #pragma unroll
    for (int m = 0; m < 2; ++m)
        #pragma unroll
        for (int i = 0; i < 4; ++i) {
            const int row = m * 16 + g * 4 + i;
            const float dn = s_den[row];
            float* orow = soft_out + (size_t)(b0 + row) * KCB + wv * 128 + q15;
            #pragma unroll
            for (int ct = 0; ct < 8; ++ct) {
                float sv = acc[m][ct][i] * dn;
                orow[ct * 16] = sv;
                csum[ct] += sv;
            }
        }
    #pragma unroll
    for (int ct = 0; ct < 8; ++ct) {
        float v = csum[ct];
        v += __shfl_xor(v, 16, 64);
        v += __shfl_xor(v, 32, 64);
        csum[ct] = v;
    }
    if (lane < 16) {
        #pragma unroll
        for (int ct = 0; ct < 8; ++ct)
            atomicAdd(avg_ws + wv * 128 + ct * 16 + lane, csum[ct]);
    }
    if (t == 0) {
        float cs = 0.f;
        #pragma unroll
        for (int r = 0; r < 32; ++r) cs += s_bestv[r];
        atomicAdd(clu_ws, cs);
    }

    // ---- Phase F: hard_quantized = emb[argmax]
    const float4* emb4 = (const float4*)emb;
    for (int idx = t; idx < 32 * 128; idx += NT2) {
        int r = idx >> 7, c = idx & 127;
        ((float4*)(hq_out + (size_t)(b0 + r) * D))[c] = emb4[(size_t)s_besti[r] * 128 + c];
    }
}

// ---------------- K3: MFMA quantized = soft @ emb (embT bf16), fused SSE
// Block: 32 rows, 8 waves, wave wv owns d-cols [64wv, 64wv+64). A staged bf16 in LDS.
__global__ __launch_bounds__(NT2, 4) void k_quant(
    const float* __restrict__ lat, const us* __restrict__ embT,
    const float* __restrict__ soft_in, const float* __restrict__ inv_ws,
    float* __restrict__ q_out, float* __restrict__ sse_ws)
{
    __shared__ __align__(16) us salds[32][516];   // bf16 soft tile (k-half), padded stride
    __shared__ float part[8];
    const int t = threadIdx.x, wv = t >> 6, lane = t & 63;
    const int q15 = lane & 15, g = lane >> 4;
    const int b0 = blockIdx.x * 32;

    f32x4 acc[2][4];
    #pragma unroll
    for (int m = 0; m < 2; ++m)
        #pragma unroll
        for (int ct = 0; ct < 4; ++ct) { f32x4 z = {0.f, 0.f, 0.f, 0.f}; acc[m][ct] = z; }

    const float4* s4 = (const float4*)soft_in;
    for (int p = 0; p < 2; ++p) {
        // stage 32 rows x 512 k of soft as bf16 into LDS
        for (int idx = t; idx < 32 * 128; idx += NT2) {
            int r = idx >> 7, c4 = idx & 127;
            float4 v = s4[(size_t)(b0 + r) * (KCB / 4) + p * 128 + c4];
            uint2 u;
            u.x = (unsigned)(us)bf16r(v.x) | ((unsigned)(us)bf16r(v.y) << 16);
            u.y = (unsigned)(us)bf16r(v.z) | ((unsigned)(us)bf16r(v.w) << 16);
            *(uint2*)&salds[r][c4 * 4] = u;
        }
        __syncthreads();

        const us* pB = embT + (size_t)(wv * 64 + q15) * KCB + p * 512;
        for (int ks = 0; ks < 16; ++ks) {
            short8v af0 = *(const short8v*)&salds[q15][ks * 32 + g * 8];
            short8v af1 = *(const short8v*)&salds[16 + q15][ks * 32 + g * 8];
            short8v bfr[4];
            #pragma unroll
            for (int ct = 0; ct < 4; ++ct)
                bfr[ct] = *(const short8v*)(pB + (size_t)ct * 16 * KCB + ks * 32 + g * 8);
            #pragma unroll
            for (int ct = 0; ct < 4; ++ct) {
                acc[0][ct] = __builtin_amdgcn_mfma_f32_16x16x32_bf16(af0, bfr[ct], acc[0][ct], 0, 0, 0);
                acc[1][ct] = __builtin_amdgcn_mfma_f32_16x16x32_bf16(af1, bfr[ct], acc[1][ct], 0, 0, 0);
            }
        }
        __syncthreads();
    }

    // epilogue: rows m*16+g*4+i, d-col = 64wv + 16ct + q15
    float sse = 0.f;
    #pragma unroll
    for (int m = 0; m < 2; ++m)
        #pragma unroll
        for (int i = 0; i < 4; ++i) {
            const int row = b0 + m * 16 + g * 4 + i;
            const float rv = inv_ws[row];
            const float* lrow = lat + (size_t)row * D + wv * 64 + q15;
            float* qrow = q_out + (size_t)row * D + wv * 64 + q15;
            #pragma unroll
            for (int ct = 0; ct < 4; ++ct) {
                float qv = acc[m][ct][i];
                qrow[ct * 16] = qv;
                float df = qv - lrow[ct * 16] * rv;
                sse += df * df;
            }
        }
    sse = wave_reduce_sum(sse);
    if (lane == 0) part[wv] = sse;
    __syncthreads();
    if (t == 0) {
        float s = 0.f;
        #pragma unroll
        for (int w = 0; w < 8; ++w) s += part[w];
        atomicAdd(sse_ws, s);
    }
}

// ---------------- K4: scalars
__global__ __launch_bounds__(NT) void k_final(
    const float* __restrict__ avg_ws, const float* __restrict__ sse_ws, const float* __restrict__ clu_ws,
    float* __restrict__ out_vq, float* __restrict__ out_ent, float* __restrict__ out_cm,
    float invB, float invBD)
{
    const int t = threadIdx.x;
    float ent = 0.f;
    for (int idx = t; idx < KCB; idx += NT) {
        float pv = avg_ws[idx] * invB;
        ent -= pv * logf(pv + 1e-10f);
    }
    ent = wave_reduce_sum(ent);
    __shared__ float part[4];
    const int wv = t >> 6, lane = t & 63;
    if (lane == 0) part[wv] = ent;
    __syncthreads();
    if (t == 0) {
        *out_ent = part[0] + part[1] + part[2] + part[3];
        *out_vq  = 1.25f * (*sse_ws) * invBD;
        *out_cm  = (*clu_ws) * invB;
    }
}

extern "C" void kernel_launch(void* const* d_in, const int* in_sizes, int n_in,
                              void* d_out, int out_size, void* d_ws, size_t ws_size,
                              hipStream_t stream)
{
    const float* lat = (const float*)d_in[0];
    const float* emb = (const float*)d_in[1];
    const int B = in_sizes[0] / D;           // 16384
    float* out = (float*)d_out;

    const size_t vq_off   = (size_t)B * D;
    const size_t ent_off  = vq_off + 1;
    const size_t argm_off = vq_off + 2;
    const size_t hq_off   = argm_off + (size_t)B;
    const size_t soft_off = hq_off + (size_t)B * D;
    const size_t cm_off   = soft_off + (size_t)B * KCB;

    us* cb_bf   = (us*)d_ws;                          // K*D bf16 (1 MB)
    us* embT_bf = cb_bf + (size_t)KCB * D;            // D*K bf16 (1 MB)
    float* fbase  = (float*)(embT_bf + (size_t)D * KCB);
    float* inv_ws = fbase;                            // B floats
    float* cbinv  = inv_ws + B;                       // K floats
    float* avg_ws = cbinv + KCB;                      // K floats
    float* sse_ws = avg_ws + KCB;                     // 1
    float* clu_ws = sse_ws + 1;                       // 1

    k_init<<<4, NT, 0, stream>>>(avg_ws, sse_ws, clu_ws);
    k_prep<<<KCB, NT, 0, stream>>>(emb, cb_bf, cbinv);
    k_tr<<<(D / 64) * (KCB / 64), NT, 0, stream>>>(emb, embT_bf);
    k_attn<<<B / 32, NT2, 0, stream>>>(lat, emb, cb_bf, cbinv, inv_ws, avg_ws, clu_ws,
                                       out + soft_off, out + argm_off, out + hq_off);
    k_quant<<<B / 32, NT2, 0, stream>>>(lat, embT_bf, out + soft_off, inv_ws, out, sse_ws);
    k_final<<<1, NT, 0, stream>>>(avg_ws, sse_ws, clu_ws,
                                  out + vq_off, out + ent_off, out + cm_off,
                                  1.0f / (float)B, 1.0f / ((float)B * (float)D));
}

// Round 4
// 299.066 us; speedup vs baseline: 2.6070x; 1.0633x over previous
//
#include <hip/hip_runtime.h>
#include <math.h>

#define D     512
#define KCB   1024
#define NT    256
#define NT2   512
#define ALPHA 10.0f
#define TAU   0.008f

typedef __attribute__((ext_vector_type(8))) short short8v;
typedef __attribute__((ext_vector_type(4))) float f32x4;
typedef unsigned short us;

__device__ __forceinline__ float wave_reduce_sum(float v) {
    #pragma unroll
    for (int off = 32; off >= 1; off >>= 1) v += __shfl_xor(v, off, 64);
    return v;
}

// fp32 -> bf16 round-to-nearest-even
__device__ __forceinline__ short bf16r(float x) {
    union { float f; unsigned u; } c; c.f = x;
    unsigned r = (c.u + 0x7FFFu + ((c.u >> 16) & 1u)) >> 16;
    return (short)r;
}

// ---------------- K0: zero ws accumulators (ws poisoned each call)
__global__ void k_init(float* __restrict__ avg, float* __restrict__ sse, float* __restrict__ clu) {
    int t = threadIdx.x + blockIdx.x * blockDim.x;
    if (t < KCB) avg[t] = 0.0f;
    if (t == 0) { *sse = 0.0f; *clu = 0.0f; }
}

// ---------------- K1: normalized codebook bf16, FRAGMENT-MAJOR swizzled layout.
// Element (k, d) -> cb[ ((k>>4)*16 + (d>>5))*512 + (((d>>3)&3)*16 + (k&15))*8 + (d&7) ]
// so a wave's MFMA B-fragment (16 rows x 8 k-slice) is one contiguous 1KB run.
__global__ __launch_bounds__(NT) void k_prep(const float* __restrict__ emb,
                                             us* __restrict__ cb, float* __restrict__ cbinv) {
    const int k = blockIdx.x, t = threadIdx.x;
    const int wv = t >> 6, lane = t & 63;
    float2 v = ((const float2*)(emb + (size_t)k * D))[t];
    float ss = wave_reduce_sum(v.x * v.x + v.y * v.y);
    __shared__ float part[4];
    __shared__ float s_i;
    if (lane == 0) part[wv] = ss;
    __syncthreads();
    if (t == 0) s_i = 1.0f / fmaxf(sqrtf(part[0] + part[1] + part[2] + part[3]), 1e-12f);
    __syncthreads();
    float inv = s_i;
    unsigned lo = (unsigned short)bf16r(v.x * inv);
    unsigned hi = (unsigned short)bf16r(v.y * inv);
    const int d = 2 * t;
    size_t idx = (((size_t)(k >> 4) * 16 + (d >> 5)) * 64 + ((d >> 3) & 3) * 16 + (k & 15)) * 8 + (d & 7);
    ((unsigned*)cb)[idx >> 1] = lo | (hi << 16);
    if (t == 0) cbinv[k] = inv;
}

// ---------------- K1b: embT bf16, FRAGMENT-MAJOR swizzled (B-operand for k_quant).
// Element (dcol, k) -> embT[ ((dcol>>4)*32 + (k>>5))*512 + (((k>>3)&3)*16 + (dcol&15))*8 + (k&7) ]
__global__ __launch_bounds__(NT) void k_tr(const float* __restrict__ emb, us* __restrict__ embT) {
    __shared__ us tile[64][65];
    const int t = threadIdx.x;
    const int k0 = (blockIdx.x & 15) * 64;
    const int d0 = (blockIdx.x >> 4) * 64;
    {
        const int r = t >> 2, cq = t & 3;
        const float4* ep = (const float4*)(emb + (size_t)(k0 + r) * D + d0 + cq * 16);
        float4 v0 = ep[0], v1 = ep[1], v2 = ep[2], v3 = ep[3];
        us* tp = &tile[r][cq * 16];
        tp[0] = (us)bf16r(v0.x); tp[1] = (us)bf16r(v0.y); tp[2] = (us)bf16r(v0.z); tp[3] = (us)bf16r(v0.w);
        tp[4] = (us)bf16r(v1.x); tp[5] = (us)bf16r(v1.y); tp[6] = (us)bf16r(v1.z); tp[7] = (us)bf16r(v1.w);
        tp[8] = (us)bf16r(v2.x); tp[9] = (us)bf16r(v2.y); tp[10] = (us)bf16r(v2.z); tp[11] = (us)bf16r(v2.w);
        tp[12] = (us)bf16r(v3.x); tp[13] = (us)bf16r(v3.y); tp[14] = (us)bf16r(v3.z); tp[15] = (us)bf16r(v3.w);
    }
    __syncthreads();
    {
        const int rd = t >> 2, kq = t & 3;
        const int dcol = d0 + rd;
        short8v w0, w1;
        #pragma unroll
        for (int j = 0; j < 8; ++j) w0[j] = (short)tile[kq * 16 + j][rd];
        #pragma unroll
        for (int j = 0; j < 8; ++j) w1[j] = (short)tile[kq * 16 + 8 + j][rd];
        const int kb0 = k0 + kq * 16, kb1 = kb0 + 8;
        size_t i0 = (((size_t)(dcol >> 4) * 32 + (kb0 >> 5)) * 64 + ((kb0 >> 3) & 3) * 16 + (dcol & 15)) * 8;
        size_t i1 = (((size_t)(dcol >> 4) * 32 + (kb1 >> 5)) * 64 + ((kb1 >> 3) & 3) * 16 + (dcol & 15)) * 8;
        *(short8v*)(embT + i0) = w0;
        *(short8v*)(embT + i1) = w1;
    }
}

// ---------------- K2: MFMA attention + softmax + fp32-rescued argmax + stats
// Block: 32 latent rows, 8 waves, wave wv owns cols [128wv, 128wv+128).
__global__ __launch_bounds__(NT2, 2) void k_attn(
    const float* __restrict__ lat, const float* __restrict__ emb,
    const us* __restrict__ cb, const float* __restrict__ cbinv,
    float* __restrict__ inv_ws, float* __restrict__ avg_ws, float* __restrict__ clu_ws,
    float* __restrict__ soft_out, float* __restrict__ argm_out, float* __restrict__ hq_out)
{
    __shared__ __align__(16) us alds[32][520];   // bf16 normalized A, padded stride
    __shared__ float s_inv[32];
    __shared__ float s_maxp[8][32];
    __shared__ float s_amax[32];
    __shared__ float s_sump[8][32];
    __shared__ float s_den[32];
    __shared__ float s_bestv[32];
    __shared__ int   s_besti[32];
    __shared__ int   s_cnt;
    __shared__ int   s_ck[512];
    __shared__ float s_cv[512];

    const int t = threadIdx.x, wv = t >> 6, lane = t & 63;
    const int q15 = lane & 15, g = lane >> 4;
    const int b0 = blockIdx.x * 32;

    // ---- Phase A: normalize 32 rows (4 per wave), store bf16 into LDS
    #pragma unroll
    for (int i = 0; i < 4; ++i) {
        int r = wv * 4 + i, grow = b0 + r;
        const float4* lp = (const float4*)(lat + (size_t)grow * D);
        float4 a = lp[2 * lane], b = lp[2 * lane + 1];
        float ss = a.x*a.x + a.y*a.y + a.z*a.z + a.w*a.w
                 + b.x*b.x + b.y*b.y + b.z*b.z + b.w*b.w;
        ss = wave_reduce_sum(ss);
        float inv = 1.0f / fmaxf(sqrtf(ss), 1e-12f);
        short8v w;
        w[0] = bf16r(a.x * inv); w[1] = bf16r(a.y * inv);
        w[2] = bf16r(a.z * inv); w[3] = bf16r(a.w * inv);
        w[4] = bf16r(b.x * inv); w[5] = bf16r(b.y * inv);
        w[6] = bf16r(b.z * inv); w[7] = bf16r(b.w * inv);
        *(short8v*)&alds[r][lane * 8] = w;
        if (lane == 0) { s_inv[r] = inv; inv_ws[grow] = inv; }
    }
    if (t == 0) s_cnt = 0;
    __syncthreads();

    // ---- Phase B: MFMA GEMM. A from LDS (bf16); B = cb fragment-major (coalesced 1KB loads).
    f32x4 acc[2][8];
    #pragma unroll
    for (int m = 0; m < 2; ++m)
        #pragma unroll
        for (int ct = 0; ct < 8; ++ct) { f32x4 z = {0.f, 0.f, 0.f, 0.f}; acc[m][ct] = z; }

    const us* pBw = cb + (size_t)(wv * 8) * 16 * 512 + (size_t)lane * 8;
    for (int ks = 0; ks < 16; ++ks) {
        short8v af0 = *(const short8v*)&alds[q15][ks * 32 + g * 8];
        short8v af1 = *(const short8v*)&alds[16 + q15][ks * 32 + g * 8];
        short8v bfr[8];
        #pragma unroll
        for (int ct = 0; ct < 8; ++ct)
            bfr[ct] = *(const short8v*)(pBw + (size_t)(ct * 16 + ks) * 512);
        #pragma unroll
        for (int ct = 0; ct < 8; ++ct) {
            acc[0][ct] = __builtin_amdgcn_mfma_f32_16x16x32_bf16(af0, bfr[ct], acc[0][ct], 0, 0, 0);
            acc[1][ct] = __builtin_amdgcn_mfma_f32_16x16x32_bf16(af1, bfr[ct], acc[1][ct], 0, 0, 0);
        }
    }
    // lane holds: rows (block-local) 16m + 4g + i, cols 128wv + 16ct + q15

    // ---- Phase C: approx row max
    #pragma unroll
    for (int m = 0; m < 2; ++m)
        #pragma unroll
        for (int i = 0; i < 4; ++i) {
            float v = acc[m][0][i];
            #pragma unroll
            for (int ct = 1; ct < 8; ++ct) v = fmaxf(v, acc[m][ct][i]);
            #pragma unroll
            for (int off = 8; off >= 1; off >>= 1) v = fmaxf(v, __shfl_xor(v, off, 64));
            if (q15 == 0) s_maxp[wv][m * 16 + g * 4 + i] = v;
        }
    __syncthreads();
    if (t < 32) {
        float v = s_maxp[0][t];
        #pragma unroll
        for (int w = 1; w < 8; ++w) v = fmaxf(v, s_maxp[w][t]);
        s_amax[t] = v;
    }
    __syncthreads();

    // ---- Phase C2: candidate gather (approx score within TAU of approx max)
    #pragma unroll
    for (int m = 0; m < 2; ++m)
        #pragma unroll
        for (int i = 0; i < 4; ++i) {
            const int row = m * 16 + g * 4 + i;
            const float thr = s_amax[row] - TAU;
            #pragma unroll
            for (int ct = 0; ct < 8; ++ct) {
                if (acc[m][ct][i] >= thr) {
                    int idx = atomicAdd(&s_cnt, 1);
                    if (idx < 512) s_ck[idx] = (row << 16) | (wv * 128 + ct * 16 + q15);
                }
            }
        }
    __syncthreads();
    const int cnt = (s_cnt < 512) ? s_cnt : 512;

    // ---- Phase C3: fp32 rescue — exact dot for each candidate (wave-parallel over d)
    for (int e = wv; e < cnt; e += 8) {
        const int pk = s_ck[e];
        const int row = pk >> 16, kk = pk & 0xFFFF;
        const float4* lp = (const float4*)(lat + (size_t)(b0 + row) * D);
        const float4* ep = (const float4*)(emb + (size_t)kk * D);
        float4 x0 = lp[2 * lane], x1 = lp[2 * lane + 1];
        float4 y0 = ep[2 * lane], y1 = ep[2 * lane + 1];
        float dp = x0.x*y0.x + x0.y*y0.y + x0.z*y0.z + x0.w*y0.w
                 + x1.x*y1.x + x1.y*y1.y + x1.z*y1.z + x1.w*y1.w;
        dp = wave_reduce_sum(dp);
        if (lane == 0) s_cv[e] = dp * s_inv[row] * cbinv[kk];
    }
    __syncthreads();
    if (t < 32) {
        float bv = -1e30f; int bi = 0x7FFFFFFF;
        for (int e = 0; e < cnt; ++e) {
            if ((s_ck[e] >> 16) == t) {
                float v = s_cv[e]; int kk = s_ck[e] & 0xFFFF;
                if (v > bv || (v == bv && kk < bi)) { bv = v; bi = kk; }
            }
        }
        s_bestv[t] = bv; s_besti[t] = bi;
        argm_out[b0 + t] = (float)bi;
    }
    __syncthreads();

    // ---- Phase D: exp + row sums
    #pragma unroll
    for (int m = 0; m < 2; ++m)
        #pragma unroll
        for (int i = 0; i < 4; ++i) {
            const float bvv = s_bestv[m * 16 + g * 4 + i];
            float s = 0.f;
            #pragma unroll
            for (int ct = 0; ct < 8; ++ct) {
                float e = __expf(ALPHA * (acc[m][ct][i] - bvv));
                acc[m][ct][i] = e;
                s += e;
            }
            #pragma unroll
            for (int off = 8; off >= 1; off >>= 1) s += __shfl_xor(s, off, 64);
            if (q15 == 0) s_sump[wv][m * 16 + g * 4 + i] = s;
        }
    __syncthreads();
    if (t < 32) {
        float s = s_sump[0][t];
        #pragma unroll
        for (int w = 1; w < 8; ++w) s += s_sump[w][t];
        s_den[t] = 1.0f / s;
    }
    __syncthreads();

    // ---- Phase E: soft_assign store + avg_probs partials + cluster metric
    float csum[8];
    #pragma unroll
    for (int ct = 0; ct < 8; ++ct) csum[ct] = 0.f;
    #pragma unroll
    for (int m = 0; m < 2; ++m)
        #pragma unroll
        for (int i = 0; i < 4; ++i) {
            const int row = m * 16 + g * 4 + i;
            const float dn = s_den[row];
            float* orow = soft_out + (size_t)(b0 + row) * KCB + wv * 128 + q15;
            #pragma unroll
            for (int ct = 0; ct < 8; ++ct) {
                float sv = acc[m][ct][i] * dn;
                orow[ct * 16] = sv;
                csum[ct] += sv;
            }
        }
    #pragma unroll
    for (int ct = 0; ct < 8; ++ct) {
        float v = csum[ct];
        v += __shfl_xor(v, 16, 64);
        v += __shfl_xor(v, 32, 64);
        csum[ct] = v;
    }
    if (lane < 16) {
        #pragma unroll
        for (int ct = 0; ct < 8; ++ct)
            atomicAdd(avg_ws + wv * 128 + ct * 16 + lane, csum[ct]);
    }
    if (t == 0) {
        float cs = 0.f;
        #pragma unroll
        for (int r = 0; r < 32; ++r) cs += s_bestv[r];
        atomicAdd(clu_ws, cs);
    }

    // ---- Phase F: hard_quantized = emb[argmax]
    const float4* emb4 = (const float4*)emb;
    for (int idx = t; idx < 32 * 128; idx += NT2) {
        int r = idx >> 7, c = idx & 127;
        ((float4*)(hq_out + (size_t)(b0 + r) * D))[c] = emb4[(size_t)s_besti[r] * 128 + c];
    }
}

// ---------------- K3: MFMA quantized = soft @ emb (embT fragment-major), fused SSE
// Block: 32 rows, 8 waves, wave wv owns d-cols [64wv, 64wv+64). A staged bf16 in LDS.
__global__ __launch_bounds__(NT2, 2) void k_quant(
    const float* __restrict__ lat, const us* __restrict__ embT,
    const float* __restrict__ soft_in, const float* __restrict__ inv_ws,
    float* __restrict__ q_out, float* __restrict__ sse_ws)
{
    __shared__ __align__(16) us salds[32][516];   // bf16 soft tile (k-half), padded stride
    __shared__ float part[8];
    const int t = threadIdx.x, wv = t >> 6, lane = t & 63;
    const int q15 = lane & 15, g = lane >> 4;
    const int b0 = blockIdx.x * 32;

    f32x4 acc[2][4];
    #pragma unroll
    for (int m = 0; m < 2; ++m)
        #pragma unroll
        for (int ct = 0; ct < 4; ++ct) { f32x4 z = {0.f, 0.f, 0.f, 0.f}; acc[m][ct] = z; }

    const float4* s4 = (const float4*)soft_in;
    for (int p = 0; p < 2; ++p) {
        // stage 32 rows x 512 k of soft as bf16 into LDS
        for (int idx = t; idx < 32 * 128; idx += NT2) {
            int r = idx >> 7, c4 = idx & 127;
            float4 v = s4[(size_t)(b0 + r) * (KCB / 4) + p * 128 + c4];
            uint2 u;
            u.x = (unsigned)(us)bf16r(v.x) | ((unsigned)(us)bf16r(v.y) << 16);
            u.y = (unsigned)(us)bf16r(v.z) | ((unsigned)(us)bf16r(v.w) << 16);
            *(uint2*)&salds[r][c4 * 4] = u;
        }
        __syncthreads();

        const us* pBw = embT + ((size_t)(wv * 128) + p * 16) * 512 + (size_t)lane * 8;
        for (int ks = 0; ks < 16; ++ks) {
            short8v af0 = *(const short8v*)&salds[q15][ks * 32 + g * 8];
            short8v af1 = *(const short8v*)&salds[16 + q15][ks * 32 + g * 8];
            short8v bfr[4];
            #pragma unroll
            for (int ct = 0; ct < 4; ++ct)
                bfr[ct] = *(const short8v*)(pBw + (size_t)(ct * 32 + ks) * 512);
            #pragma unroll
            for (int ct = 0; ct < 4; ++ct) {
                acc[0][ct] = __builtin_amdgcn_mfma_f32_16x16x32_bf16(af0, bfr[ct], acc[0][ct], 0, 0, 0);
                acc[1][ct] = __builtin_amdgcn_mfma_f32_16x16x32_bf16(af1, bfr[ct], acc[1][ct], 0, 0, 0);
            }
        }
        __syncthreads();
    }

    // epilogue: rows m*16+g*4+i, d-col = 64wv + 16ct + q15
    float sse = 0.f;
    #pragma unroll
    for (int m = 0; m < 2; ++m)
        #pragma unroll
        for (int i = 0; i < 4; ++i) {
            const int row = b0 + m * 16 + g * 4 + i;
            const float rv = inv_ws[row];
            const float* lrow = lat + (size_t)row * D + wv * 64 + q15;
            float* qrow = q_out + (size_t)row * D + wv * 64 + q15;
            #pragma unroll
            for (int ct = 0; ct < 4; ++ct) {
                float qv = acc[m][ct][i];
                qrow[ct * 16] = qv;
                float df = qv - lrow[ct * 16] * rv;
                sse += df * df;
            }
        }
    sse = wave_reduce_sum(sse);
    if (lane == 0) part[wv] = sse;
    __syncthreads();
    if (t == 0) {
        float s = 0.f;
        #pragma unroll
        for (int w = 0; w < 8; ++w) s += part[w];
        atomicAdd(sse_ws, s);
    }
}

// ---------------- K4: scalars
__global__ __launch_bounds__(NT) void k_final(
    const float* __restrict__ avg_ws, const float* __restrict__ sse_ws, const float* __restrict__ clu_ws,
    float* __restrict__ out_vq, float* __restrict__ out_ent, float* __restrict__ out_cm,
    float invB, float invBD)
{
    const int t = threadIdx.x;
    float ent = 0.f;
    for (int idx = t; idx < KCB; idx += NT) {
        float pv = avg_ws[idx] * invB;
        ent -= pv * logf(pv + 1e-10f);
    }
    ent = wave_reduce_sum(ent);
    __shared__ float part[4];
    const int wv = t >> 6, lane = t & 63;
    if (lane == 0) part[wv] = ent;
    __syncthreads();
    if (t == 0) {
        *out_ent = part[0] + part[1] + part[2] + part[3];
        *out_vq  = 1.25f * (*sse_ws) * invBD;
        *out_cm  = (*clu_ws) * invB;
    }
}

extern "C" void kernel_launch(void* const* d_in, const int* in_sizes, int n_in,
                              void* d_out, int out_size, void* d_ws, size_t ws_size,
                              hipStream_t stream)
{
    const float* lat = (const float*)d_in[0];
    const float* emb = (const float*)d_in[1];
    const int B = in_sizes[0] / D;           // 16384
    float* out = (float*)d_out;

    const size_t vq_off   = (size_t)B * D;
    const size_t ent_off  = vq_off + 1;
    const size_t argm_off = vq_off + 2;
    const size_t hq_off   = argm_off + (size_t)B;
    const size_t soft_off = hq_off + (size_t)B * D;
    const size_t cm_off   = soft_off + (size_t)B * KCB;

    us* cb_bf   = (us*)d_ws;                          // K*D bf16 (1 MB), fragment-major
    us* embT_bf = cb_bf + (size_t)KCB * D;            // D*K bf16 (1 MB), fragment-major
    float* fbase  = (float*)(embT_bf + (size_t)D * KCB);
    float* inv_ws = fbase;                            // B floats
    float* cbinv  = inv_ws + B;                       // K floats
    float* avg_ws = cbinv + KCB;                      // K floats
    float* sse_ws = avg_ws + KCB;                     // 1
    float* clu_ws = sse_ws + 1;                       // 1

    k_init<<<4, NT, 0, stream>>>(avg_ws, sse_ws, clu_ws);
    k_prep<<<KCB, NT, 0, stream>>>(emb, cb_bf, cbinv);
    k_tr<<<(D / 64) * (KCB / 64), NT, 0, stream>>>(emb, embT_bf);
    k_attn<<<B / 32, NT2, 0, stream>>>(lat, emb, cb_bf, cbinv, inv_ws, avg_ws, clu_ws,
                                       out + soft_off, out + argm_off, out + hq_off);
    k_quant<<<B / 32, NT2, 0, stream>>>(lat, embT_bf, out + soft_off, inv_ws, out, sse_ws);
    k_final<<<1, NT, 0, stream>>>(avg_ws, sse_ws, clu_ws,
                                  out + vq_off, out + ent_off, out + cm_off,
                                  1.0f / (float)B, 1.0f / ((float)B * (float)D));
}

// Round 5
// 294.256 us; speedup vs baseline: 2.6496x; 1.0163x over previous
//
#include <hip/hip_runtime.h>
#include <math.h>

#define D     512
#define KCB   1024
#define NT    256
#define NT2   512
#define ALPHA 10.0f
#define TAU   0.008f
#define PSTR  1040   // pool row stride in us (bf16) units

typedef __attribute__((ext_vector_type(8))) short short8v;
typedef __attribute__((ext_vector_type(4))) float f32x4;
typedef unsigned short us;

__device__ __forceinline__ float wave_reduce_sum(float v) {
    #pragma unroll
    for (int off = 32; off >= 1; off >>= 1) v += __shfl_xor(v, off, 64);
    return v;
}

// fp32 -> bf16 round-to-nearest-even
__device__ __forceinline__ short bf16r(float x) {
    union { float f; unsigned u; } c; c.f = x;
    unsigned r = (c.u + 0x7FFFu + ((c.u >> 16) & 1u)) >> 16;
    return (short)r;
}

// ---------------- K0: zero ws accumulators (ws poisoned each call)
__global__ void k_init(float* __restrict__ avg, float* __restrict__ sse, float* __restrict__ clu) {
    int t = threadIdx.x + blockIdx.x * blockDim.x;
    if (t < KCB) avg[t] = 0.0f;
    if (t == 0) { *sse = 0.0f; *clu = 0.0f; }
}

// ---------------- K1: normalized codebook bf16, FRAGMENT-MAJOR swizzled layout.
// Element (k, d) -> cb[ ((k>>4)*16 + (d>>5))*512 + (((d>>3)&3)*16 + (k&15))*8 + (d&7) ]
__global__ __launch_bounds__(NT) void k_prep(const float* __restrict__ emb,
                                             us* __restrict__ cb, float* __restrict__ cbinv) {
    const int k = blockIdx.x, t = threadIdx.x;
    const int wv = t >> 6, lane = t & 63;
    float2 v = ((const float2*)(emb + (size_t)k * D))[t];
    float ss = wave_reduce_sum(v.x * v.x + v.y * v.y);
    __shared__ float part[4];
    __shared__ float s_i;
    if (lane == 0) part[wv] = ss;
    __syncthreads();
    if (t == 0) s_i = 1.0f / fmaxf(sqrtf(part[0] + part[1] + part[2] + part[3]), 1e-12f);
    __syncthreads();
    float inv = s_i;
    unsigned lo = (unsigned short)bf16r(v.x * inv);
    unsigned hi = (unsigned short)bf16r(v.y * inv);
    const int d = 2 * t;
    size_t idx = (((size_t)(k >> 4) * 16 + (d >> 5)) * 64 + ((d >> 3) & 3) * 16 + (k & 15)) * 8 + (d & 7);
    ((unsigned*)cb)[idx >> 1] = lo | (hi << 16);
    if (t == 0) cbinv[k] = inv;
}

// ---------------- K1b: embT bf16, FRAGMENT-MAJOR swizzled (B-operand for quant GEMM).
// Element (dcol, k) -> embT[ ((dcol>>4)*32 + (k>>5))*512 + (((k>>3)&3)*16 + (dcol&15))*8 + (k&7) ]
__global__ __launch_bounds__(NT) void k_tr(const float* __restrict__ emb, us* __restrict__ embT) {
    __shared__ us tile[64][65];
    const int t = threadIdx.x;
    const int k0 = (blockIdx.x & 15) * 64;
    const int d0 = (blockIdx.x >> 4) * 64;
    {
        const int r = t >> 2, cq = t & 3;
        const float4* ep = (const float4*)(emb + (size_t)(k0 + r) * D + d0 + cq * 16);
        float4 v0 = ep[0], v1 = ep[1], v2 = ep[2], v3 = ep[3];
        us* tp = &tile[r][cq * 16];
        tp[0] = (us)bf16r(v0.x); tp[1] = (us)bf16r(v0.y); tp[2] = (us)bf16r(v0.z); tp[3] = (us)bf16r(v0.w);
        tp[4] = (us)bf16r(v1.x); tp[5] = (us)bf16r(v1.y); tp[6] = (us)bf16r(v1.z); tp[7] = (us)bf16r(v1.w);
        tp[8] = (us)bf16r(v2.x); tp[9] = (us)bf16r(v2.y); tp[10] = (us)bf16r(v2.z); tp[11] = (us)bf16r(v2.w);
        tp[12] = (us)bf16r(v3.x); tp[13] = (us)bf16r(v3.y); tp[14] = (us)bf16r(v3.z); tp[15] = (us)bf16r(v3.w);
    }
    __syncthreads();
    {
        const int rd = t >> 2, kq = t & 3;
        const int dcol = d0 + rd;
        short8v w0, w1;
        #pragma unroll
        for (int j = 0; j < 8; ++j) w0[j] = (short)tile[kq * 16 + j][rd];
        #pragma unroll
        for (int j = 0; j < 8; ++j) w1[j] = (short)tile[kq * 16 + 8 + j][rd];
        const int kb0 = k0 + kq * 16, kb1 = kb0 + 8;
        size_t i0 = (((size_t)(dcol >> 4) * 32 + (kb0 >> 5)) * 64 + ((kb0 >> 3) & 3) * 16 + (dcol & 15)) * 8;
        size_t i1 = (((size_t)(dcol >> 4) * 32 + (kb1 >> 5)) * 64 + ((kb1 >> 3) & 3) * 16 + (dcol & 15)) * 8;
        *(short8v*)(embT + i0) = w0;
        *(short8v*)(embT + i1) = w1;
    }
}

// ---------------- K2: FUSED attention + softmax + rescue-argmax + stats + quant GEMM + SSE
// Block: 32 latent rows, 8 waves.
// Attention: wave wv owns cols [128wv, 128wv+128). Quant: wave wv owns d-cols [64wv, 64wv+64).
__global__ __launch_bounds__(NT2, 2) void k_fused(
    const float* __restrict__ lat, const float* __restrict__ emb,
    const us* __restrict__ cb, const us* __restrict__ embT, const float* __restrict__ cbinv,
    float* __restrict__ avg_ws, float* __restrict__ clu_ws, float* __restrict__ sse_ws,
    float* __restrict__ q_out, float* __restrict__ soft_out,
    float* __restrict__ argm_out, float* __restrict__ hq_out)
{
    extern __shared__ __align__(16) us pool[];   // [32][PSTR]: A bf16 (cols 0..511), later soft bf16 (cols 0..1023)
    __shared__ float s_inv[32];
    __shared__ float s_maxp[8][32];
    __shared__ float s_amax[32];
    __shared__ float s_sump[8][32];
    __shared__ float s_den[32];
    __shared__ float s_bestv[32];
    __shared__ int   s_besti[32];
    __shared__ int   s_cnt;
    __shared__ int   s_ck[512];
    __shared__ float s_cv[512];
    __shared__ float part[8];

    const int t = threadIdx.x, wv = t >> 6, lane = t & 63;
    const int q15 = lane & 15, g = lane >> 4;
    const int b0 = blockIdx.x * 32;

    // ---- Phase A: normalize 32 rows (4 per wave), bf16 into pool. Loads issued up-front.
    float4 ra[4], rb[4];
    #pragma unroll
    for (int i = 0; i < 4; ++i) {
        const float4* lp = (const float4*)(lat + (size_t)(b0 + wv * 4 + i) * D);
        ra[i] = lp[2 * lane]; rb[i] = lp[2 * lane + 1];
    }
    #pragma unroll
    for (int i = 0; i < 4; ++i) {
        int r = wv * 4 + i;
        float4 a = ra[i], b = rb[i];
        float ss = a.x*a.x + a.y*a.y + a.z*a.z + a.w*a.w
                 + b.x*b.x + b.y*b.y + b.z*b.z + b.w*b.w;
        ss = wave_reduce_sum(ss);
        float inv = 1.0f / fmaxf(sqrtf(ss), 1e-12f);
        short8v w;
        w[0] = bf16r(a.x * inv); w[1] = bf16r(a.y * inv);
        w[2] = bf16r(a.z * inv); w[3] = bf16r(a.w * inv);
        w[4] = bf16r(b.x * inv); w[5] = bf16r(b.y * inv);
        w[6] = bf16r(b.z * inv); w[7] = bf16r(b.w * inv);
        *(short8v*)&pool[(size_t)r * PSTR + lane * 8] = w;
        if (lane == 0) s_inv[r] = inv;
    }
    if (t == 0) s_cnt = 0;
    __syncthreads();

    // ---- Phase B: attention MFMA, software-pipelined B loads (even/odd double buffer).
    f32x4 acc[2][8];
    #pragma unroll
    for (int m = 0; m < 2; ++m)
        #pragma unroll
        for (int ct = 0; ct < 8; ++ct) { f32x4 z = {0.f, 0.f, 0.f, 0.f}; acc[m][ct] = z; }

    const us* pBw = cb + (size_t)(wv * 8) * 16 * 512 + (size_t)lane * 8;
    #define LDB_A(ks, ct) (*(const short8v*)(pBw + (size_t)((ct) * 16 + (ks)) * 512))
    #define LDA_A(row, ks) (*(const short8v*)&pool[(size_t)(row) * PSTR + (ks) * 32 + g * 8])

    short8v bE[8], bO[8];
    #pragma unroll
    for (int ct = 0; ct < 8; ++ct) bE[ct] = LDB_A(0, ct);
    for (int ks = 0; ks < 16; ks += 2) {
        #pragma unroll
        for (int ct = 0; ct < 8; ++ct) bO[ct] = LDB_A(ks + 1, ct);
        short8v af0 = LDA_A(q15, ks), af1 = LDA_A(16 + q15, ks);
        #pragma unroll
        for (int ct = 0; ct < 8; ++ct) {
            acc[0][ct] = __builtin_amdgcn_mfma_f32_16x16x32_bf16(af0, bE[ct], acc[0][ct], 0, 0, 0);
            acc[1][ct] = __builtin_amdgcn_mfma_f32_16x16x32_bf16(af1, bE[ct], acc[1][ct], 0, 0, 0);
        }
        const int ksn = (ks + 2 < 16) ? ks + 2 : 0;
        #pragma unroll
        for (int ct = 0; ct < 8; ++ct) bE[ct] = LDB_A(ksn, ct);
        af0 = LDA_A(q15, ks + 1); af1 = LDA_A(16 + q15, ks + 1);
        #pragma unroll
        for (int ct = 0; ct < 8; ++ct) {
            acc[0][ct] = __builtin_amdgcn_mfma_f32_16x16x32_bf16(af0, bO[ct], acc[0][ct], 0, 0, 0);
            acc[1][ct] = __builtin_amdgcn_mfma_f32_16x16x32_bf16(af1, bO[ct], acc[1][ct], 0, 0, 0);
        }
    }
    // lane holds: rows (block-local) 16m + 4g + i, cols 128wv + 16ct + q15

    // ---- Phase C: approx row max
    #pragma unroll
    for (int m = 0; m < 2; ++m)
        #pragma unroll
        for (int i = 0; i < 4; ++i) {
            float v = acc[m][0][i];
            #pragma unroll
            for (int ct = 1; ct < 8; ++ct) v = fmaxf(v, acc[m][ct][i]);
            #pragma unroll
            for (int off = 8; off >= 1; off >>= 1) v = fmaxf(v, __shfl_xor(v, off, 64));
            if (q15 == 0) s_maxp[wv][m * 16 + g * 4 + i] = v;
        }
    __syncthreads();
    if (t < 32) {
        float v = s_maxp[0][t];
        #pragma unroll
        for (int w = 1; w < 8; ++w) v = fmaxf(v, s_maxp[w][t]);
        s_amax[t] = v;
    }
    __syncthreads();

    // ---- Phase C2: candidate gather (approx score within TAU of approx max)
    #pragma unroll
    for (int m = 0; m < 2; ++m)
        #pragma unroll
        for (int i = 0; i < 4; ++i) {
            const int row = m * 16 + g * 4 + i;
            const float thr = s_amax[row] - TAU;
            #pragma unroll
            for (int ct = 0; ct < 8; ++ct) {
                if (acc[m][ct][i] >= thr) {
                    int idx = atomicAdd(&s_cnt, 1);
                    if (idx < 512) s_ck[idx] = (row << 16) | (wv * 128 + ct * 16 + q15);
                }
            }
        }
    __syncthreads();
    const int cnt = (s_cnt < 512) ? s_cnt : 512;

    // ---- Phase C3: fp32 rescue — exact dot per candidate (wave-parallel over d)
    for (int e = wv; e < cnt; e += 8) {
        const int pk = s_ck[e];
        const int row = pk >> 16, kk = pk & 0xFFFF;
        const float4* lp = (const float4*)(lat + (size_t)(b0 + row) * D);
        const float4* ep = (const float4*)(emb + (size_t)kk * D);
        float4 x0 = lp[2 * lane], x1 = lp[2 * lane + 1];
        float4 y0 = ep[2 * lane], y1 = ep[2 * lane + 1];
        float dp = x0.x*y0.x + x0.y*y0.y + x0.z*y0.z + x0.w*y0.w
                 + x1.x*y1.x + x1.y*y1.y + x1.z*y1.z + x1.w*y1.w;
        dp = wave_reduce_sum(dp);
        if (lane == 0) s_cv[e] = dp * s_inv[row] * cbinv[kk];
    }
    __syncthreads();
    if (t < 32) {
        float bv = -1e30f; int bi = 0x7FFFFFFF;
        for (int e = 0; e < cnt; ++e) {
            if ((s_ck[e] >> 16) == t) {
                float v = s_cv[e]; int kk = s_ck[e] & 0xFFFF;
                if (v > bv || (v == bv && kk < bi)) { bv = v; bi = kk; }
            }
        }
        s_bestv[t] = bv; s_besti[t] = bi;
        argm_out[b0 + t] = (float)bi;
    }
    __syncthreads();

    // ---- Phase D: exp + row sums
    #pragma unroll
    for (int m = 0; m < 2; ++m)
        #pragma unroll
        for (int i = 0; i < 4; ++i) {
            const float bvv = s_bestv[m * 16 + g * 4 + i];
            float s = 0.f;
            #pragma unroll
            for (int ct = 0; ct < 8; ++ct) {
                float e = __expf(ALPHA * (acc[m][ct][i] - bvv));
                acc[m][ct][i] = e;
                s += e;
            }
            #pragma unroll
            for (int off = 8; off >= 1; off >>= 1) s += __shfl_xor(s, off, 64);
            if (q15 == 0) s_sump[wv][m * 16 + g * 4 + i] = s;
        }
    __syncthreads();
    if (t < 32) {
        float s = s_sump[0][t];
        #pragma unroll
        for (int w = 1; w < 8; ++w) s += s_sump[w][t];
        s_den[t] = 1.0f / s;
    }
    __syncthreads();

    // ---- Phase E: soft_assign -> global (f32) + pool (bf16, A-operand for quant) + stats
    float csum[8];
    #pragma unroll
    for (int ct = 0; ct < 8; ++ct) csum[ct] = 0.f;
    #pragma unroll
    for (int m = 0; m < 2; ++m)
        #pragma unroll
        for (int i = 0; i < 4; ++i) {
            const int row = m * 16 + g * 4 + i;
            const float dn = s_den[row];
            float* orow = soft_out + (size_t)(b0 + row) * KCB + wv * 128 + q15;
            us* prow = &pool[(size_t)row * PSTR + wv * 128 + q15];
            #pragma unroll
            for (int ct = 0; ct < 8; ++ct) {
                float sv = acc[m][ct][i] * dn;
                orow[ct * 16] = sv;
                prow[ct * 16] = (us)bf16r(sv);
                csum[ct] += sv;
            }
        }
    #pragma unroll
    for (int ct = 0; ct < 8; ++ct) {
        float v = csum[ct];
        v += __shfl_xor(v, 16, 64);
        v += __shfl_xor(v, 32, 64);
        csum[ct] = v;
    }
    if (lane < 16) {
        #pragma unroll
        for (int ct = 0; ct < 8; ++ct)
            atomicAdd(avg_ws + wv * 128 + ct * 16 + lane, csum[ct]);
    }
    if (t == 0) {
        float cs = 0.f;
        #pragma unroll
        for (int r = 0; r < 32; ++r) cs += s_bestv[r];
        atomicAdd(clu_ws, cs);
    }
    __syncthreads();

    // ---- Phase F: hard_quantized = emb[argmax] (issued before quant GEMM; latency hides under MFMAs)
    const float4* emb4 = (const float4*)emb;
    #pragma unroll
    for (int u = 0; u < 8; ++u) {
        int idx = t + u * NT2;
        int r = idx >> 7, c = idx & 127;
        ((float4*)(hq_out + (size_t)(b0 + r) * D))[c] = emb4[(size_t)s_besti[r] * 128 + c];
    }

    // ---- Phase G: quantized = soft @ emb, MFMA, software-pipelined. Wave wv: d-cols [64wv, 64wv+64).
    f32x4 qac[2][4];
    #pragma unroll
    for (int m = 0; m < 2; ++m)
        #pragma unroll
        for (int ct = 0; ct < 4; ++ct) { f32x4 z = {0.f, 0.f, 0.f, 0.f}; qac[m][ct] = z; }

    const us* pBq = embT + (size_t)(wv * 128) * 512 + (size_t)lane * 8;
    #define LDB_Q(ks, ct) (*(const short8v*)(pBq + (size_t)((ct) * 32 + (ks)) * 512))
    #define LDA_Q(row, ks) (*(const short8v*)&pool[(size_t)(row) * PSTR + (ks) * 32 + g * 8])

    short8v qE[4], qO[4];
    #pragma unroll
    for (int ct = 0; ct < 4; ++ct) qE[ct] = LDB_Q(0, ct);
    for (int ks = 0; ks < 32; ks += 2) {
        #pragma unroll
        for (int ct = 0; ct < 4; ++ct) qO[ct] = LDB_Q(ks + 1, ct);
        short8v af0 = LDA_Q(q15, ks), af1 = LDA_Q(16 + q15, ks);
        #pragma unroll
        for (int ct = 0; ct < 4; ++ct) {
            qac[0][ct] = __builtin_amdgcn_mfma_f32_16x16x32_bf16(af0, qE[ct], qac[0][ct], 0, 0, 0);
            qac[1][ct] = __builtin_amdgcn_mfma_f32_16x16x32_bf16(af1, qE[ct], qac[1][ct], 0, 0, 0);
        }
        const int ksn = (ks + 2 < 32) ? ks + 2 : 0;
        #pragma unroll
        for (int ct = 0; ct < 4; ++ct) qE[ct] = LDB_Q(ksn, ct);
        af0 = LDA_Q(q15, ks + 1); af1 = LDA_Q(16 + q15, ks + 1);
        #pragma unroll
        for (int ct = 0; ct < 4; ++ct) {
            qac[0][ct] = __builtin_amdgcn_mfma_f32_16x16x32_bf16(af0, qO[ct], qac[0][ct], 0, 0, 0);
            qac[1][ct] = __builtin_amdgcn_mfma_f32_16x16x32_bf16(af1, qO[ct], qac[1][ct], 0, 0, 0);
        }
    }

    // ---- Phase H: q write + fused SSE((q - ln)^2)
    float sse = 0.f;
    #pragma unroll
    for (int m = 0; m < 2; ++m)
        #pragma unroll
        for (int i = 0; i < 4; ++i) {
            const int rloc = m * 16 + g * 4 + i;
            const int row = b0 + rloc;
            const float rv = s_inv[rloc];
            const float* lrow = lat + (size_t)row * D + wv * 64 + q15;
            float* qrow = q_out + (size_t)row * D + wv * 64 + q15;
            #pragma unroll
            for (int ct = 0; ct < 4; ++ct) {
                float qv = qac[m][ct][i];
                qrow[ct * 16] = qv;
                float df = qv - lrow[ct * 16] * rv;
                sse += df * df;
            }
        }
    sse = wave_reduce_sum(sse);
    if (lane == 0) part[wv] = sse;
    __syncthreads();
    if (t == 0) {
        float s = 0.f;
        #pragma unroll
        for (int w = 0; w < 8; ++w) s += part[w];
        atomicAdd(sse_ws, s);
    }
    #undef LDB_A
    #undef LDA_A
    #undef LDB_Q
    #undef LDA_Q
}

// ---------------- K4: scalars
__global__ __launch_bounds__(NT) void k_final(
    const float* __restrict__ avg_ws, const float* __restrict__ sse_ws, const float* __restrict__ clu_ws,
    float* __restrict__ out_vq, float* __restrict__ out_ent, float* __restrict__ out_cm,
    float invB, float invBD)
{
    const int t = threadIdx.x;
    float ent = 0.f;
    for (int idx = t; idx < KCB; idx += NT) {
        float pv = avg_ws[idx] * invB;
        ent -= pv * logf(pv + 1e-10f);
    }
    ent = wave_reduce_sum(ent);
    __shared__ float part[4];
    const int wv = t >> 6, lane = t & 63;
    if (lane == 0) part[wv] = ent;
    __syncthreads();
    if (t == 0) {
        *out_ent = part[0] + part[1] + part[2] + part[3];
        *out_vq  = 1.25f * (*sse_ws) * invBD;
        *out_cm  = (*clu_ws) * invB;
    }
}

extern "C" void kernel_launch(void* const* d_in, const int* in_sizes, int n_in,
                              void* d_out, int out_size, void* d_ws, size_t ws_size,
                              hipStream_t stream)
{
    const float* lat = (const float*)d_in[0];
    const float* emb = (const float*)d_in[1];
    const int B = in_sizes[0] / D;           // 16384
    float* out = (float*)d_out;

    const size_t vq_off   = (size_t)B * D;
    const size_t ent_off  = vq_off + 1;
    const size_t argm_off = vq_off + 2;
    const size_t hq_off   = argm_off + (size_t)B;
    const size_t soft_off = hq_off + (size_t)B * D;
    const size_t cm_off   = soft_off + (size_t)B * KCB;

    us* cb_bf   = (us*)d_ws;                          // K*D bf16 (1 MB), fragment-major
    us* embT_bf = cb_bf + (size_t)KCB * D;            // D*K bf16 (1 MB), fragment-major
    float* fbase  = (float*)(embT_bf + (size_t)D * KCB);
    float* cbinv  = fbase;                            // K floats
    float* avg_ws = cbinv + KCB;                      // K floats
    float* sse_ws = avg_ws + KCB;                     // 1
    float* clu_ws = sse_ws + 1;                       // 1

    const int lds_bytes = 32 * PSTR * 2;              // 66,560 B dynamic pool

    k_init<<<4, NT, 0, stream>>>(avg_ws, sse_ws, clu_ws);
    k_prep<<<KCB, NT, 0, stream>>>(emb, cb_bf, cbinv);
    k_tr<<<(D / 64) * (KCB / 64), NT, 0, stream>>>(emb, embT_bf);
    k_fused<<<B / 32, NT2, lds_bytes, stream>>>(lat, emb, cb_bf, embT_bf, cbinv,
                                                avg_ws, clu_ws, sse_ws,
                                                out, out + soft_off, out + argm_off, out + hq_off);
    k_final<<<1, NT, 0, stream>>>(avg_ws, sse_ws, clu_ws,
                                  out + vq_off, out + ent_off, out + cm_off,
                                  1.0f / (float)B, 1.0f / ((float)B * (float)D));
}

// Round 6
// 277.324 us; speedup vs baseline: 2.8113x; 1.0611x over previous
//
#include <hip/hip_runtime.h>
#include <math.h>

#define D     512
#define KCB   1024
#define NT    256
#define NT2   512
#define RB    64          // latent rows per block
#define ALPHA 10.0f
#define TAU   0.008f
#define PSTR  1040        // pool row stride in us (bf16) units

typedef __attribute__((ext_vector_type(8))) short short8v;
typedef __attribute__((ext_vector_type(4))) float f32x4;
typedef unsigned short us;

__device__ __forceinline__ float wave_reduce_sum(float v) {
    #pragma unroll
    for (int off = 32; off >= 1; off >>= 1) v += __shfl_xor(v, off, 64);
    return v;
}

// fp32 -> bf16 round-to-nearest-even
__device__ __forceinline__ short bf16r(float x) {
    union { float f; unsigned u; } c; c.f = x;
    unsigned r = (c.u + 0x7FFFu + ((c.u >> 16) & 1u)) >> 16;
    return (short)r;
}

// ---------------- K1: merged prep — normalized cb (fragment-major), raw embT (fragment-major),
// cbinv, and zeroing of avg/sse/clu. One block per codebook row k.
// cb element (k,d)    -> (((k>>4)*16 + (d>>5))*64 + ((d>>3)&3)*16 + (k&15))*8 + (d&7)
// embT element (d,k)  -> (((d>>4)*32 + (k>>5))*64 + ((k>>3)&3)*16 + (d&15))*8 + (k&7)
__global__ __launch_bounds__(NT) void k_prep2(const float* __restrict__ emb,
                                              us* __restrict__ cb, us* __restrict__ embT,
                                              float* __restrict__ cbinv,
                                              float* __restrict__ avg_ws,
                                              float* __restrict__ sse, float* __restrict__ clu) {
    const int k = blockIdx.x, t = threadIdx.x;
    const int wv = t >> 6, lane = t & 63;
    if (k < 4) avg_ws[k * NT + t] = 0.0f;
    if (k == 0 && t == 0) { *sse = 0.0f; *clu = 0.0f; }

    float2 v = ((const float2*)(emb + (size_t)k * D))[t];
    float ss = wave_reduce_sum(v.x * v.x + v.y * v.y);
    __shared__ float part[4];
    __shared__ float s_i;
    if (lane == 0) part[wv] = ss;
    __syncthreads();
    if (t == 0) s_i = 1.0f / fmaxf(sqrtf(part[0] + part[1] + part[2] + part[3]), 1e-12f);
    __syncthreads();
    float inv = s_i;
    const int d = 2 * t;
    // normalized cb
    unsigned lo = (unsigned short)bf16r(v.x * inv);
    unsigned hi = (unsigned short)bf16r(v.y * inv);
    size_t idx = (((size_t)(k >> 4) * 16 + (d >> 5)) * 64 + ((d >> 3) & 3) * 16 + (k & 15)) * 8 + (d & 7);
    ((unsigned*)cb)[idx >> 1] = lo | (hi << 16);
    // raw embT
    size_t j0 = (((size_t)(d >> 4) * 32 + (k >> 5)) * 64 + ((k >> 3) & 3) * 16 + (d & 15)) * 8 + (k & 7);
    embT[j0]     = (us)bf16r(v.x);
    embT[j0 + 8] = (us)bf16r(v.y);
    if (t == 0) cbinv[k] = inv;
}

// ---------------- K2: FUSED attention + softmax + rescue-argmax + stats + quant GEMM + SSE
// Block: 64 latent rows, 8 waves.
// Attention: wave wv owns cols [128wv, 128wv+128). Quant: wave wv owns d-cols [64wv, 64wv+64).
__global__ __launch_bounds__(NT2, 2) void k_fused(
    const float* __restrict__ lat, const float* __restrict__ emb,
    const us* __restrict__ cb, const us* __restrict__ embT, const float* __restrict__ cbinv,
    float* __restrict__ avg_ws, float* __restrict__ part_ws, int use_part,
    float* __restrict__ clu_ws, float* __restrict__ sse_ws,
    float* __restrict__ q_out, float* __restrict__ soft_out,
    float* __restrict__ argm_out, float* __restrict__ hq_out)
{
    extern __shared__ __align__(16) us pool[];   // [RB][PSTR]: A bf16 (cols 0..511), later soft bf16 (cols 0..1023)
    __shared__ float s_inv[RB];
    __shared__ float s_maxp[8][RB];
    __shared__ float s_amax[RB];
    __shared__ float s_sump[8][RB];
    __shared__ float s_den[RB];
    __shared__ float s_bestv[RB];
    __shared__ int   s_besti[RB];
    __shared__ int   s_cnt;
    __shared__ int   s_ck[1024];
    __shared__ float s_cv[1024];
    __shared__ float part[8];

    const int t = threadIdx.x, wv = t >> 6, lane = t & 63;
    const int q15 = lane & 15, g = lane >> 4;
    const int b0 = blockIdx.x * RB;

    // ---- Phase A: normalize RB rows (8 per wave), bf16 into pool. Loads issued up-front.
    float4 ra[8], rb[8];
    #pragma unroll
    for (int i = 0; i < 8; ++i) {
        const float4* lp = (const float4*)(lat + (size_t)(b0 + wv * 8 + i) * D);
        ra[i] = lp[2 * lane]; rb[i] = lp[2 * lane + 1];
    }
    #pragma unroll
    for (int i = 0; i < 8; ++i) {
        int r = wv * 8 + i;
        float4 a = ra[i], b = rb[i];
        float ss = a.x*a.x + a.y*a.y + a.z*a.z + a.w*a.w
                 + b.x*b.x + b.y*b.y + b.z*b.z + b.w*b.w;
        ss = wave_reduce_sum(ss);
        float inv = 1.0f / fmaxf(sqrtf(ss), 1e-12f);
        short8v w;
        w[0] = bf16r(a.x * inv); w[1] = bf16r(a.y * inv);
        w[2] = bf16r(a.z * inv); w[3] = bf16r(a.w * inv);
        w[4] = bf16r(b.x * inv); w[5] = bf16r(b.y * inv);
        w[6] = bf16r(b.z * inv); w[7] = bf16r(b.w * inv);
        *(short8v*)&pool[(size_t)r * PSTR + lane * 8] = w;
        if (lane == 0) s_inv[r] = inv;
    }
    if (t == 0) s_cnt = 0;
    __syncthreads();

    // ---- Phase B: attention MFMA, software-pipelined B loads (even/odd double buffer).
    f32x4 acc[4][8];
    #pragma unroll
    for (int m = 0; m < 4; ++m)
        #pragma unroll
        for (int ct = 0; ct < 8; ++ct) { f32x4 z = {0.f, 0.f, 0.f, 0.f}; acc[m][ct] = z; }

    const us* pBw = cb + (size_t)(wv * 8) * 16 * 512 + (size_t)lane * 8;
    #define LDB_A(ks, ct) (*(const short8v*)(pBw + (size_t)((ct) * 16 + (ks)) * 512))
    #define LDA_A(row, ks) (*(const short8v*)&pool[(size_t)(row) * PSTR + (ks) * 32 + g * 8])

    short8v bE[8], bO[8];
    #pragma unroll
    for (int ct = 0; ct < 8; ++ct) bE[ct] = LDB_A(0, ct);
    for (int ks = 0; ks < 16; ks += 2) {
        #pragma unroll
        for (int ct = 0; ct < 8; ++ct) bO[ct] = LDB_A(ks + 1, ct);
        {
            short8v af0 = LDA_A(q15, ks), af1 = LDA_A(16 + q15, ks);
            short8v af2 = LDA_A(32 + q15, ks), af3 = LDA_A(48 + q15, ks);
            #pragma unroll
            for (int ct = 0; ct < 8; ++ct) {
                acc[0][ct] = __builtin_amdgcn_mfma_f32_16x16x32_bf16(af0, bE[ct], acc[0][ct], 0, 0, 0);
                acc[1][ct] = __builtin_amdgcn_mfma_f32_16x16x32_bf16(af1, bE[ct], acc[1][ct], 0, 0, 0);
                acc[2][ct] = __builtin_amdgcn_mfma_f32_16x16x32_bf16(af2, bE[ct], acc[2][ct], 0, 0, 0);
                acc[3][ct] = __builtin_amdgcn_mfma_f32_16x16x32_bf16(af3, bE[ct], acc[3][ct], 0, 0, 0);
            }
        }
        const int ksn = (ks + 2 < 16) ? ks + 2 : 0;
        #pragma unroll
        for (int ct = 0; ct < 8; ++ct) bE[ct] = LDB_A(ksn, ct);
        {
            short8v af0 = LDA_A(q15, ks + 1), af1 = LDA_A(16 + q15, ks + 1);
            short8v af2 = LDA_A(32 + q15, ks + 1), af3 = LDA_A(48 + q15, ks + 1);
            #pragma unroll
            for (int ct = 0; ct < 8; ++ct) {
                acc[0][ct] = __builtin_amdgcn_mfma_f32_16x16x32_bf16(af0, bO[ct], acc[0][ct], 0, 0, 0);
                acc[1][ct] = __builtin_amdgcn_mfma_f32_16x16x32_bf16(af1, bO[ct], acc[1][ct], 0, 0, 0);
                acc[2][ct] = __builtin_amdgcn_mfma_f32_16x16x32_bf16(af2, bO[ct], acc[2][ct], 0, 0, 0);
                acc[3][ct] = __builtin_amdgcn_mfma_f32_16x16x32_bf16(af3, bO[ct], acc[3][ct], 0, 0, 0);
            }
        }
    }
    // lane holds: rows (block-local) 16m + 4g + i, cols 128wv + 16ct + q15

    // ---- Phase C: approx row max
    #pragma unroll
    for (int m = 0; m < 4; ++m)
        #pragma unroll
        for (int i = 0; i < 4; ++i) {
            float v = acc[m][0][i];
            #pragma unroll
            for (int ct = 1; ct < 8; ++ct) v = fmaxf(v, acc[m][ct][i]);
            #pragma unroll
            for (int off = 8; off >= 1; off >>= 1) v = fmaxf(v, __shfl_xor(v, off, 64));
            if (q15 == 0) s_maxp[wv][m * 16 + g * 4 + i] = v;
        }
    __syncthreads();
    if (t < RB) {
        float v = s_maxp[0][t];
        #pragma unroll
        for (int w = 1; w < 8; ++w) v = fmaxf(v, s_maxp[w][t]);
        s_amax[t] = v;
    }
    __syncthreads();

    // ---- Phase C2: candidate gather (approx score within TAU of approx max)
    #pragma unroll
    for (int m = 0; m < 4; ++m)
        #pragma unroll
        for (int i = 0; i < 4; ++i) {
            const int row = m * 16 + g * 4 + i;
            const float thr = s_amax[row] - TAU;
            #pragma unroll
            for (int ct = 0; ct < 8; ++ct) {
                if (acc[m][ct][i] >= thr) {
                    int idx = atomicAdd(&s_cnt, 1);
                    if (idx < 1024) s_ck[idx] = (row << 16) | (wv * 128 + ct * 16 + q15);
                }
            }
        }
    __syncthreads();
    const int cnt = (s_cnt < 1024) ? s_cnt : 1024;

    // ---- Phase C3: fp32 rescue — exact dot per candidate (wave-parallel over d)
    for (int e = wv; e < cnt; e += 8) {
        const int pk = s_ck[e];
        const int row = pk >> 16, kk = pk & 0xFFFF;
        const float4* lp = (const float4*)(lat + (size_t)(b0 + row) * D);
        const float4* ep = (const float4*)(emb + (size_t)kk * D);
        float4 x0 = lp[2 * lane], x1 = lp[2 * lane + 1];
        float4 y0 = ep[2 * lane], y1 = ep[2 * lane + 1];
        float dp = x0.x*y0.x + x0.y*y0.y + x0.z*y0.z + x0.w*y0.w
                 + x1.x*y1.x + x1.y*y1.y + x1.z*y1.z + x1.w*y1.w;
        dp = wave_reduce_sum(dp);
        if (lane == 0) s_cv[e] = dp * s_inv[row] * cbinv[kk];
    }
    __syncthreads();
    if (t < RB) {
        float bv = -1e30f; int bi = 0x7FFFFFFF;
        for (int e = 0; e < cnt; ++e) {
            if ((s_ck[e] >> 16) == t) {
                float v = s_cv[e]; int kk = s_ck[e] & 0xFFFF;
                if (v > bv || (v == bv && kk < bi)) { bv = v; bi = kk; }
            }
        }
        s_bestv[t] = bv; s_besti[t] = bi;
        argm_out[b0 + t] = (float)bi;
    }
    __syncthreads();

    // ---- Phase D: exp + row sums
    #pragma unroll
    for (int m = 0; m < 4; ++m)
        #pragma unroll
        for (int i = 0; i < 4; ++i) {
            const float bvv = s_bestv[m * 16 + g * 4 + i];
            float s = 0.f;
            #pragma unroll
            for (int ct = 0; ct < 8; ++ct) {
                float e = __expf(ALPHA * (acc[m][ct][i] - bvv));
                acc[m][ct][i] = e;
                s += e;
            }
            #pragma unroll
            for (int off = 8; off >= 1; off >>= 1) s += __shfl_xor(s, off, 64);
            if (q15 == 0) s_sump[wv][m * 16 + g * 4 + i] = s;
        }
    __syncthreads();
    if (t < RB) {
        float s = s_sump[0][t];
        #pragma unroll
        for (int w = 1; w < 8; ++w) s += s_sump[w][t];
        s_den[t] = 1.0f / s;
    }
    __syncthreads();

    // ---- Phase E: soft_assign -> global (f32) + pool (bf16, A-operand for quant) + stats
    float csum[8];
    #pragma unroll
    for (int ct = 0; ct < 8; ++ct) csum[ct] = 0.f;
    #pragma unroll
    for (int m = 0; m < 4; ++m)
        #pragma unroll
        for (int i = 0; i < 4; ++i) {
            const int row = m * 16 + g * 4 + i;
            const float dn = s_den[row];
            float* orow = soft_out + (size_t)(b0 + row) * KCB + wv * 128 + q15;
            us* prow = &pool[(size_t)row * PSTR + wv * 128 + q15];
            #pragma unroll
            for (int ct = 0; ct < 8; ++ct) {
                float sv = acc[m][ct][i] * dn;
                orow[ct * 16] = sv;
                prow[ct * 16] = (us)bf16r(sv);
                csum[ct] += sv;
            }
        }
    #pragma unroll
    for (int ct = 0; ct < 8; ++ct) {
        float v = csum[ct];
        v += __shfl_xor(v, 16, 64);
        v += __shfl_xor(v, 32, 64);
        csum[ct] = v;
    }
    if (use_part) {
        if (lane < 16) {
            #pragma unroll
            for (int ct = 0; ct < 8; ++ct)
                part_ws[(size_t)blockIdx.x * KCB + wv * 128 + ct * 16 + lane] = csum[ct];
        }
    } else {
        if (lane < 16) {
            #pragma unroll
            for (int ct = 0; ct < 8; ++ct)
                atomicAdd(avg_ws + wv * 128 + ct * 16 + lane, csum[ct]);
        }
    }
    if (t == 0) {
        float cs = 0.f;
        #pragma unroll
        for (int r = 0; r < RB; ++r) cs += s_bestv[r];
        atomicAdd(clu_ws, cs);
    }
    __syncthreads();

    // ---- Phase F: hard_quantized = emb[argmax] (issued before quant GEMM; latency hides under MFMAs)
    const float4* emb4 = (const float4*)emb;
    #pragma unroll
    for (int u = 0; u < 16; ++u) {
        int idx = t + u * NT2;
        int r = idx >> 7, c = idx & 127;
        ((float4*)(hq_out + (size_t)(b0 + r) * D))[c] = emb4[(size_t)s_besti[r] * 128 + c];
    }

    // ---- Phase G: quantized = soft @ emb, MFMA, software-pipelined. Wave wv: d-cols [64wv, 64wv+64).
    f32x4 qac[4][4];
    #pragma unroll
    for (int m = 0; m < 4; ++m)
        #pragma unroll
        for (int ct = 0; ct < 4; ++ct) { f32x4 z = {0.f, 0.f, 0.f, 0.f}; qac[m][ct] = z; }

    const us* pBq = embT + (size_t)(wv * 128) * 512 + (size_t)lane * 8;
    #define LDB_Q(ks, ct) (*(const short8v*)(pBq + (size_t)((ct) * 32 + (ks)) * 512))
    #define LDA_Q(row, ks) (*(const short8v*)&pool[(size_t)(row) * PSTR + (ks) * 32 + g * 8])

    short8v qE[4], qO[4];
    #pragma unroll
    for (int ct = 0; ct < 4; ++ct) qE[ct] = LDB_Q(0, ct);
    for (int ks = 0; ks < 32; ks += 2) {
        #pragma unroll
        for (int ct = 0; ct < 4; ++ct) qO[ct] = LDB_Q(ks + 1, ct);
        {
            short8v af0 = LDA_Q(q15, ks), af1 = LDA_Q(16 + q15, ks);
            short8v af2 = LDA_Q(32 + q15, ks), af3 = LDA_Q(48 + q15, ks);
            #pragma unroll
            for (int ct = 0; ct < 4; ++ct) {
                qac[0][ct] = __builtin_amdgcn_mfma_f32_16x16x32_bf16(af0, qE[ct], qac[0][ct], 0, 0, 0);
                qac[1][ct] = __builtin_amdgcn_mfma_f32_16x16x32_bf16(af1, qE[ct], qac[1][ct], 0, 0, 0);
                qac[2][ct] = __builtin_amdgcn_mfma_f32_16x16x32_bf16(af2, qE[ct], qac[2][ct], 0, 0, 0);
                qac[3][ct] = __builtin_amdgcn_mfma_f32_16x16x32_bf16(af3, qE[ct], qac[3][ct], 0, 0, 0);
            }
        }
        const int ksn = (ks + 2 < 32) ? ks + 2 : 0;
        #pragma unroll
        for (int ct = 0; ct < 4; ++ct) qE[ct] = LDB_Q(ksn, ct);
        {
            short8v af0 = LDA_Q(q15, ks + 1), af1 = LDA_Q(16 + q15, ks + 1);
            short8v af2 = LDA_Q(32 + q15, ks + 1), af3 = LDA_Q(48 + q15, ks + 1);
            #pragma unroll
            for (int ct = 0; ct < 4; ++ct) {
                qac[0][ct] = __builtin_amdgcn_mfma_f32_16x16x32_bf16(af0, qO[ct], qac[0][ct], 0, 0, 0);
                qac[1][ct] = __builtin_amdgcn_mfma_f32_16x16x32_bf16(af1, qO[ct], qac[1][ct], 0, 0, 0);
                qac[2][ct] = __builtin_amdgcn_mfma_f32_16x16x32_bf16(af2, qO[ct], qac[2][ct], 0, 0, 0);
                qac[3][ct] = __builtin_amdgcn_mfma_f32_16x16x32_bf16(af3, qO[ct], qac[3][ct], 0, 0, 0);
            }
        }
    }

    // ---- Phase H: q write + fused SSE((q - ln)^2)
    float sse = 0.f;
    #pragma unroll
    for (int m = 0; m < 4; ++m)
        #pragma unroll
        for (int i = 0; i < 4; ++i) {
            const int rloc = m * 16 + g * 4 + i;
            const int row = b0 + rloc;
            const float rv = s_inv[rloc];
            const float* lrow = lat + (size_t)row * D + wv * 64 + q15;
            float* qrow = q_out + (size_t)row * D + wv * 64 + q15;
            #pragma unroll
            for (int ct = 0; ct < 4; ++ct) {
                float qv = qac[m][ct][i];
                qrow[ct * 16] = qv;
                float df = qv - lrow[ct * 16] * rv;
                sse += df * df;
            }
        }
    sse = wave_reduce_sum(sse);
    if (lane == 0) part[wv] = sse;
    __syncthreads();
    if (t == 0) {
        float s = 0.f;
        #pragma unroll
        for (int w = 0; w < 8; ++w) s += part[w];
        atomicAdd(sse_ws, s);
    }
    #undef LDB_A
    #undef LDA_A
    #undef LDB_Q
    #undef LDA_Q
}

// ---------------- K3: reduce avg partials (16 blocks; 4 col-groups x 4 row-groups)
__global__ __launch_bounds__(NT) void k_avg(const float* __restrict__ part_ws, float* __restrict__ avg_ws,
                                            int nblk) {
    const int c  = (blockIdx.x & 3) * NT + threadIdx.x;
    const int r0 = (blockIdx.x >> 2) * (nblk / 4);
    const int r1 = r0 + nblk / 4;
    float s = 0.f;
    for (int r = r0; r < r1; ++r) s += part_ws[(size_t)r * KCB + c];
    atomicAdd(avg_ws + c, s);
}

// ---------------- K4: scalars
__global__ __launch_bounds__(NT) void k_final(
    const float* __restrict__ avg_ws, const float* __restrict__ sse_ws, const float* __restrict__ clu_ws,
    float* __restrict__ out_vq, float* __restrict__ out_ent, float* __restrict__ out_cm,
    float invB, float invBD)
{
    const int t = threadIdx.x;
    float ent = 0.f;
    for (int idx = t; idx < KCB; idx += NT) {
        float pv = avg_ws[idx] * invB;
        ent -= pv * logf(pv + 1e-10f);
    }
    ent = wave_reduce_sum(ent);
    __shared__ float part[4];
    const int wv = t >> 6, lane = t & 63;
    if (lane == 0) part[wv] = ent;
    __syncthreads();
    if (t == 0) {
        *out_ent = part[0] + part[1] + part[2] + part[3];
        *out_vq  = 1.25f * (*sse_ws) * invBD;
        *out_cm  = (*clu_ws) * invB;
    }
}

extern "C" void kernel_launch(void* const* d_in, const int* in_sizes, int n_in,
                              void* d_out, int out_size, void* d_ws, size_t ws_size,
                              hipStream_t stream)
{
    const float* lat = (const float*)d_in[0];
    const float* emb = (const float*)d_in[1];
    const int B = in_sizes[0] / D;           // 16384
    float* out = (float*)d_out;

    const size_t vq_off   = (size_t)B * D;
    const size_t ent_off  = vq_off + 1;
    const size_t argm_off = vq_off + 2;
    const size_t hq_off   = argm_off + (size_t)B;
    const size_t soft_off = hq_off + (size_t)B * D;
    const size_t cm_off   = soft_off + (size_t)B * KCB;

    const int nblk = B / RB;                          // 256 blocks

    us* cb_bf   = (us*)d_ws;                          // K*D bf16 (1 MB), fragment-major
    us* embT_bf = cb_bf + (size_t)KCB * D;            // D*K bf16 (1 MB), fragment-major
    float* fbase  = (float*)(embT_bf + (size_t)D * KCB);
    float* cbinv  = fbase;                            // K floats
    float* avg_ws = cbinv + KCB;                      // K floats
    float* sse_ws = avg_ws + KCB;                     // 1
    float* clu_ws = sse_ws + 1;                       // 1
    float* part_ws = clu_ws + 1;                      // nblk*K floats (1 MB) if it fits

    const size_t base_bytes = (size_t)((char*)part_ws - (char*)d_ws);
    const int use_part = (ws_size >= base_bytes + (size_t)nblk * KCB * 4) ? 1 : 0;

    const int lds_bytes = RB * PSTR * 2;              // 133,120 B dynamic pool

    k_prep2<<<KCB, NT, 0, stream>>>(emb, cb_bf, embT_bf, cbinv, avg_ws, sse_ws, clu_ws);
    k_fused<<<nblk, NT2, lds_bytes, stream>>>(lat, emb, cb_bf, embT_bf, cbinv,
                                              avg_ws, part_ws, use_part, clu_ws, sse_ws,
                                              out, out + soft_off, out + argm_off, out + hq_off);
    if (use_part) k_avg<<<16, NT, 0, stream>>>(part_ws, avg_ws, nblk);
    k_final<<<1, NT, 0, stream>>>(avg_ws, sse_ws, clu_ws,
                                  out + vq_off, out + ent_off, out + cm_off,
                                  1.0f / (float)B, 1.0f / ((float)B * (float)D));
}